// Round 10
// baseline (1048.884 us; speedup 1.0000x reference)
//
#include <hip/hip_runtime.h>
#include <hip/hip_bf16.h>

#define CI 192
#define LL_ 4096

typedef __bf16 v8bf __attribute__((ext_vector_type(8)));
typedef float  v4f  __attribute__((ext_vector_type(4)));
typedef float  v8f  __attribute__((ext_vector_type(8)));
typedef unsigned short v8us __attribute__((ext_vector_type(8)));

__device__ __forceinline__ unsigned short f2bf(float v){
  unsigned int u = __float_as_uint(v);
  return (unsigned short)((u + 0x7FFFu + ((u >> 16) & 1u)) >> 16);
}

__global__ __launch_bounds__(256) void k_zero(float* __restrict__ p, int n){
  int i = blockIdx.x*256 + threadIdx.x;
  if (i < n) p[i] = 0.f;
}

// ------------------------------------------------ K1: RMSNorm + in_proj (tiled GEMM, 48-o tiles)
__global__ __launch_bounds__(256) void k_rms_inproj(const float* __restrict__ x,
    const float* __restrict__ rmsw, const float* __restrict__ ipw,
    float* __restrict__ xc, float* __restrict__ zT){
  int og = blockIdx.x & 7; int lt = (blockIdx.x >> 3) & 63; int b = blockIdx.x >> 9;
  int l0 = lt << 6;
  __shared__ float xt[64][97];
  __shared__ float wt[96*48];
  __shared__ float rr[64];
  __shared__ float rw[96];
  int tid = threadIdx.x;
  for (int idx = tid; idx < 6144; idx += 256){ int r = idx/96, d = idx - r*96;
    xt[r][d] = x[((size_t)b*4096 + l0 + r)*96 + d]; }
  if (tid < 96) rw[tid] = rmsw[tid];
  int o0 = og*48;
  for (int idx = tid; idx < 4608; idx += 256){ int o = idx%48, d = idx/48;
    wt[d*48 + o] = ipw[(size_t)(o0 + o)*96 + d]; }
  __syncthreads();
  if (tid < 64){
    float s = 0.f;
    for (int d = 0; d < 96; d++){ float v = xt[tid][d]; s += v*v; }
    rr[tid] = rsqrtf(s*(1.0f/96.0f) + 1e-5f);
  }
  __syncthreads();
  for (int idx = tid; idx < 6144; idx += 256){ int r = idx/96, d = idx - r*96;
    xt[r][d] *= rr[r]*rw[d]; }
  __syncthreads();
  int l = tid & 63, grp = tid >> 6;
  float acc[12];
  #pragma unroll
  for (int j = 0; j < 12; j++) acc[j] = 0.f;
  for (int d = 0; d < 96; d++){
    float xv = xt[l][d];
    const float* wr = &wt[d*48 + grp*12];
    #pragma unroll
    for (int j = 0; j < 12; j += 4){
      float4 w4 = *(const float4*)&wr[j];
      acc[j]   += xv*w4.x; acc[j+1] += xv*w4.y;
      acc[j+2] += xv*w4.z; acc[j+3] += xv*w4.w;
    }
  }
  #pragma unroll
  for (int j = 0; j < 12; j++){
    int o = o0 + grp*12 + j;
    if (o < 192) xc[((size_t)b*192 + o)*4096 + l0 + l] = acc[j];
    else         zT[((size_t)b*192 + (o-192))*4096 + l0 + l] = acc[j];
  }
}

// ------------------------------------------------ K2: forward rfft2 (ortho) + fused Haar DWT
__global__ __launch_bounds__(256) void k_dft_fwd(const float* __restrict__ xc,
    float* __restrict__ fre, float* __restrict__ fim, float* __restrict__ fab,
    float* __restrict__ ll, float* __restrict__ lh, float* __restrict__ hl, float* __restrict__ hh){
  int plane = blockIdx.x;
  __shared__ float sxT[64*65];
  __shared__ float t1r[64*34], t1i[64*34];
  __shared__ float tabr[16], tabi[16];
  __shared__ float ct64[64], st64[64];
  int tid = threadIdx.x;
  const float* X = xc + (size_t)plane*4096;
  for (int i = tid; i < 4096; i += 256){ int h = i >> 6, w = i & 63; sxT[w*65 + h] = X[i]; }
  if (tid < 16){ tabr[tid] = cospif((float)tid/8.0f); tabi[tid] = -sinpif((float)tid/8.0f); }
  if (tid < 64){ ct64[tid] = cospif((float)tid/32.0f); st64[tid] = sinpif((float)tid/32.0f); }
  __syncthreads();
  {
    size_t qbase = (size_t)plane*1024;
    for (int idx = tid; idx < 1024; idx += 256){
      int y2 = idx >> 5, x2 = idx & 31;
      float a_ = sxT[(2*x2)*65 + 2*y2],     b_ = sxT[(2*x2+1)*65 + 2*y2];
      float c_ = sxT[(2*x2)*65 + 2*y2+1],   d_ = sxT[(2*x2+1)*65 + 2*y2+1];
      ll[qbase + idx] = (a_+b_+c_+d_)*0.5f; lh[qbase + idx] = (a_-b_+c_-d_)*0.5f;
      hl[qbase + idx] = (a_+b_-c_-d_)*0.5f; hh[qbase + idx] = (a_-b_-c_+d_)*0.5f;
    }
  }
  {
    int hp = tid & 31, g = tid >> 5;
    float a0r[4], a0i[4], a1r[4], a1i[4];
    #pragma unroll
    for (int j = 0; j < 4; j++){ a0r[j]=0.f; a0i[j]=0.f; a1r[j]=0.f; a1i[j]=0.f; }
    float s32_0 = 0.f, s32_1 = 0.f;
    for (int w = 0; w < 64; w++){
      float xv0 = sxT[w*65 + hp];
      float xv1 = sxT[w*65 + hp + 32];
      int m0 = (w*g) & 15;
      float twr = tabr[m0], twi = tabi[m0];
      int ms = w & 15;
      float str = tabr[ms], sti = tabi[ms];
      #pragma unroll
      for (int j = 0; j < 4; j++){
        a0r[j] += xv0*twr; a0i[j] += xv0*twi;
        a1r[j] += xv1*twr; a1i[j] += xv1*twi;
        float nr = twr*str - twi*sti;
        float ni = twr*sti + twi*str;
        twr = nr; twi = ni;
      }
      if (g == 0){ float sg = (w & 1) ? -1.f : 1.f; s32_0 += xv0*sg; s32_1 += xv1*sg; }
    }
    #pragma unroll
    for (int j = 0; j < 4; j++){
      int k = 4*g + j;
      t1r[hp*34 + k] = a0r[j];        t1i[hp*34 + k] = a0i[j];
      t1r[(hp+32)*34 + k] = a1r[j];   t1i[(hp+32)*34 + k] = a1i[j];
    }
    if (g == 0){
      t1r[hp*34 + 32] = s32_0;      t1i[hp*34 + 32] = 0.f;
      t1r[(hp+32)*34 + 32] = s32_1; t1i[(hp+32)*34 + 32] = 0.f;
    }
  }
  __syncthreads();
  {
    int fp = tid & 31, g = tid >> 5;
    float stepr = cospif((float)fp/32.0f), stepi = -sinpif((float)fp/32.0f);
    float a0r[4], a0i[4], a1r[4], a1i[4];
    #pragma unroll
    for (int j = 0; j < 4; j++){ a0r[j]=0.f; a0i[j]=0.f; a1r[j]=0.f; a1i[j]=0.f; }
    float b0r=0.f, b0i=0.f, b1r=0.f, b1i=0.f;
    for (int hb = 0; hb < 4; hb++){
      int m = ((hb*16)*fp) & 63;
      float twr = ct64[m], twi = -st64[m];
      for (int hh2 = 0; hh2 < 16; hh2++){
        int h = hb*16 + hh2;
        float sg = (h & 1) ? -1.f : 1.f;
        #pragma unroll
        for (int j = 0; j < 4; j++){
          float Tr = t1r[h*34 + 4*g + j], Ti = t1i[h*34 + 4*g + j];
          float pr = Tr*twr - Ti*twi;
          float pi = Tr*twi + Ti*twr;
          a0r[j] += pr; a0i[j] += pi;
          a1r[j] += sg*pr; a1i[j] += sg*pi;
        }
        if (g == 0){
          float Tr = t1r[h*34 + 32], Ti = t1i[h*34 + 32];
          float pr = Tr*twr - Ti*twi, pi = Tr*twi + Ti*twr;
          b0r += pr; b0i += pi; b1r += sg*pr; b1i += sg*pi;
        }
        float nr = twr*stepr - twi*stepi, ni = twr*stepi + twi*stepr;
        twr = nr; twi = ni;
      }
    }
    size_t base = (size_t)plane*2112;
    #pragma unroll
    for (int j = 0; j < 4; j++){
      int k = 4*g + j;
      float r0 = a0r[j]*(1.f/64.f), i0 = a0i[j]*(1.f/64.f);
      float r1 = a1r[j]*(1.f/64.f), i1 = a1i[j]*(1.f/64.f);
      fre[base + fp*33 + k] = r0; fim[base + fp*33 + k] = i0;
      fab[base + fp*33 + k] = sqrtf(r0*r0 + i0*i0);
      fre[base + (fp+32)*33 + k] = r1; fim[base + (fp+32)*33 + k] = i1;
      fab[base + (fp+32)*33 + k] = sqrtf(r1*r1 + i1*i1);
    }
    if (g == 0){
      float r0 = b0r*(1.f/64.f), i0 = b0i*(1.f/64.f);
      float r1 = b1r*(1.f/64.f), i1 = b1i*(1.f/64.f);
      fre[base + fp*33 + 32] = r0; fim[base + fp*33 + 32] = i0;
      fab[base + fp*33 + 32] = sqrtf(r0*r0 + i0*i0);
      fre[base + (fp+32)*33 + 32] = r1; fim[base + (fp+32)*33 + 32] = i1;
      fab[base + (fp+32)*33 + 32] = sqrtf(r1*r1 + i1*i1);
    }
  }
}

// ------------------------------------------------ K3: m = gelu(W1 @ |xf| + b1)  (LDS weights)
__global__ __launch_bounds__(256) void k_cmix1(const float* __restrict__ fab,
    const float* __restrict__ w1, const float* __restrict__ b1, float* __restrict__ m){
  int bid = blockIdx.x;
  int pt = bid % 9; int og = (bid/9) % 24; int b = bid/216;
  int tid = threadIdx.x;
  int p = pt*256 + tid; bool act = p < 2112;
  __shared__ float wl[192*8];
  for (int idx = tid; idx < 1536; idx += 256){ int o = idx & 7, c = idx >> 3;
    wl[c*8 + o] = w1[(size_t)(og*8 + o)*192 + c]; }
  __syncthreads();
  float acc[8];
  #pragma unroll
  for (int o = 0; o < 8; o++) acc[o] = b1[og*8 + o];
  const float* xb = fab + (size_t)b*CI*2112 + p;
  for (int c = 0; c < 192; c++){
    float xv = act ? xb[(size_t)c*2112] : 0.f;
    float4 wa = *(const float4*)&wl[c*8];
    float4 wb4 = *(const float4*)&wl[c*8 + 4];
    acc[0] += xv*wa.x;  acc[1] += xv*wa.y;  acc[2] += xv*wa.z;  acc[3] += xv*wa.w;
    acc[4] += xv*wb4.x; acc[5] += xv*wb4.y; acc[6] += xv*wb4.z; acc[7] += xv*wb4.w;
  }
  if (act){
    #pragma unroll
    for (int o = 0; o < 8; o++){
      float a = acc[o];
      m[((size_t)b*192 + og*8 + o)*2112 + p] = 0.5f*a*(1.0f + erff(a*0.70710678118654752f));
    }
  }
}

// ------------------------------------------------ K4: mag = W2 @ m + b2; in-place (LDS weights)
__global__ __launch_bounds__(256) void k_cmix2(const float* __restrict__ m,
    const float* __restrict__ w2, const float* __restrict__ bi2,
    float* __restrict__ fre, float* __restrict__ fim, const float* __restrict__ fab){
  int bid = blockIdx.x;
  int pt = bid % 9; int og = (bid/9) % 24; int b = bid/216;
  int tid = threadIdx.x;
  int p = pt*256 + tid; bool act = p < 2112;
  __shared__ float wl[192*8];
  for (int idx = tid; idx < 1536; idx += 256){ int o = idx & 7, c = idx >> 3;
    wl[c*8 + o] = w2[(size_t)(og*8 + o)*192 + c]; }
  __syncthreads();
  float acc[8];
  #pragma unroll
  for (int o = 0; o < 8; o++) acc[o] = bi2[og*8 + o];
  const float* xb = m + (size_t)b*CI*2112 + p;
  for (int c = 0; c < 192; c++){
    float xv = act ? xb[(size_t)c*2112] : 0.f;
    float4 wa = *(const float4*)&wl[c*8];
    float4 wb4 = *(const float4*)&wl[c*8 + 4];
    acc[0] += xv*wa.x;  acc[1] += xv*wa.y;  acc[2] += xv*wa.z;  acc[3] += xv*wa.w;
    acc[4] += xv*wb4.x; acc[5] += xv*wb4.y; acc[6] += xv*wb4.z; acc[7] += xv*wb4.w;
  }
  if (act){
    #pragma unroll
    for (int o = 0; o < 8; o++){
      size_t id = ((size_t)b*192 + og*8 + o)*2112 + p;
      float ab = fab[id];
      float re, im;
      if (ab > 1e-30f){ float sc = acc[o]/ab; re = sc*fre[id]; im = sc*fim[id]; }
      else { re = acc[o]; im = 0.f; }
      fre[id] = re; fim[id] = im;
    }
  }
}

// ------------------------------------------------ K5b: convert weights -> bf16 [q][oc][ic]
__global__ __launch_bounds__(256) void k_cvt_w(const float* __restrict__ ww,
    unsigned short* __restrict__ wqb2){
  int idx = blockIdx.x*256 + threadIdx.x;
  if (idx >= 331776) return;
  int ic = idx % 192; int rest = idx / 192;
  int oc = rest % 192; int q = rest / 192;
  wqb2[idx] = f2bf(ww[((size_t)oc*192 + ic)*9 + q]);
}

// ------------------------------------------------ K5c: transpose lhb -> bf16 [img][pix][ic]
__global__ __launch_bounds__(256) void k_prep_lhT(const float* __restrict__ lhb,
    unsigned short* __restrict__ lhT){
  int id = blockIdx.x*256 + threadIdx.x;          // 294912 total
  int pix = id & 1023;
  int icg = (id >> 10) % 24;
  int img = id / 24576;
  const float* s = lhb + (size_t)img*196608 + (size_t)(icg*8)*1024 + pix;
  v8us v;
  #pragma unroll
  for (int j = 0; j < 8; j++) v[j] = f2bf(s[(size_t)j*1024]);
  *(v8us*)&lhT[((size_t)img*1024 + pix)*192 + icg*8] = v;
}

// ------------------------------------------------ K6: 3x3 full conv via bf16 MFMA
__global__ __launch_bounds__(256) void k_wconv_mfma(const unsigned short* __restrict__ lhT,
    const unsigned short* __restrict__ wqb2, float* __restrict__ wnew){
  int bid = blockIdx.x;
  int nt = bid % 3; int mt = (bid/3) & 15; int img = bid/48;
  int o0 = nt*64;
  __shared__ __align__(16) unsigned short sm_us[26112];  // 52224 B: A band [136 pix][192 ic], swizzled
  unsigned short* Aband = sm_us;
  float* T = (float*)sm_us;                 // epilogue alias [64 m][65]
  int tid = threadIdx.x;
  int lane = tid & 63, wv = tid >> 6;
  int quad = lane >> 4, n16 = lane & 15;
  const unsigned short* wrow = wqb2 + ((size_t)(o0 + 16*wv + n16))*192 + quad*8;
  v8us bcur[6], bnxt[6];
  #pragma unroll
  for (int icc = 0; icc < 6; icc++) bcur[icc] = *(const v8us*)&wrow[icc*32];
  for (int i = tid; i < 3264; i += 256) ((v8us*)sm_us)[i] = (v8us){0,0,0,0,0,0,0,0};
  __syncthreads();
  const unsigned short* base = lhT + (size_t)img*196608;
  for (int idx = tid; idx < 3072; idx += 256){
    int r = idx / 768; int t = idx - r*768;
    int pc = t / 24;   int icg = t - pc*24;
    int gr = 2*mt - 1 + r;
    if (gr >= 0 && gr < 32){
      v8us v = *(const v8us*)&base[((size_t)gr*32 + pc)*192 + icg*8];
      int pix = r*34 + 1 + pc;
      *(v8us*)&Aband[pix*192 + ((icg*8) ^ ((pix & 7) << 3))] = v;
    }
  }
  __syncthreads();
  v4f acc[4];
  #pragma unroll
  for (int t2 = 0; t2 < 4; t2++) acc[t2] = (v4f){0.f,0.f,0.f,0.f};
  #pragma unroll
  for (int q = 0; q < 9; q++){
    int ky = q/3, kx = q - ky*3;
    if (q < 8){
      #pragma unroll
      for (int icc = 0; icc < 6; icc++)
        bnxt[icc] = *(const v8us*)&wrow[(size_t)(q+1)*36864 + icc*32];
    }
    #pragma unroll
    for (int icc = 0; icc < 6; icc++){
      int c0 = icc*32;
      v8bf bv = __builtin_bit_cast(v8bf, bcur[icc]);
      #pragma unroll
      for (int t2 = 0; t2 < 4; t2++){
        int mm = t2*16 + n16;
        int pix = ((mm >> 5) + ky)*34 + (mm & 31) + kx;
        const unsigned short* Ap = &Aband[pix*192 + ((c0 + quad*8) ^ ((pix & 7) << 3))];
        v8bf av = __builtin_bit_cast(v8bf, *(const v8us*)Ap);
        acc[t2] = __builtin_amdgcn_mfma_f32_16x16x32_bf16(av, bv, acc[t2], 0, 0, 0);
      }
    }
    #pragma unroll
    for (int icc = 0; icc < 6; icc++) bcur[icc] = bnxt[icc];
  }
  __syncthreads();
  #pragma unroll
  for (int t2 = 0; t2 < 4; t2++)
    #pragma unroll
    for (int r = 0; r < 4; r++)
      T[(16*t2 + quad*4 + r)*65 + 16*wv + n16] = acc[t2][r];
  __syncthreads();
  float* outb = wnew + (size_t)img*196608;
  for (int idx = tid; idx < 4096; idx += 256){
    int mm = idx & 63, oc = idx >> 6;
    outb[(size_t)(o0 + oc)*1024 + mt*64 + mm] = T[mm*65 + oc];
  }
}

// ------------------------------------------------ K7 (fused): irfft2 + combine + depthwise3x3 + SiLU -> ab, aT
__global__ __launch_bounds__(256) void k_ifwd(const float* __restrict__ fre2,
    const float* __restrict__ fim2, const float* __restrict__ xc,
    const float* __restrict__ ll, const float* __restrict__ wnew, const float* __restrict__ wb,
    const float* __restrict__ dww, const float* __restrict__ dwb,
    float* __restrict__ ab, float* __restrict__ aT){
  int plane = blockIdx.x;
  int c = plane % 192;
  __shared__ __align__(16) float sm[13504];   // 54016 B -> still 3 blocks/CU
  float* gr  = sm;             // [64][36]
  float* gi  = sm + 2304;
  float* ur  = sm + 4608;      // [64][36]
  float* ui  = sm + 6912;
  float* sx2 = sm + 9216;      // [64][65]
  float* t64r = sm + 13376; float* t64i = sm + 13440;
  float* scratch = sm;         // epilogue alias [64][65] (gr/gi dead by then)
  int tid = threadIdx.x;
  {
    size_t gbase = (size_t)plane*2112;
    for (int idx = tid; idx < 528; idx += 256){
      float4 vr_ = *(const float4*)&fre2[gbase + 4*idx];
      float4 vi_ = *(const float4*)&fim2[gbase + 4*idx];
      #pragma unroll
      for (int e = 0; e < 4; e++){
        int i = 4*idx + e;
        int f = i/33, k = i - f*33;
        float re = (e==0)?vr_.x:((e==1)?vr_.y:((e==2)?vr_.z:vr_.w));
        float im = (e==0)?vi_.x:((e==1)?vi_.y:((e==2)?vi_.z:vi_.w));
        gr[f*36 + k] = re; gi[f*36 + k] = im;
      }
    }
  }
  if (tid < 64){ t64r[tid] = cospif((float)tid/32.0f); t64i[tid] = sinpif((float)tid/32.0f); }
  __syncthreads();
  {
    int hp = tid & 31, g = tid >> 5;
    float stepr = cospif((float)hp/32.0f), stepi = sinpif((float)hp/32.0f);
    v4f a0r = (v4f)0.f, a0i = (v4f)0.f, a1r = (v4f)0.f, a1i = (v4f)0.f;
    float b0r=0.f, b0i=0.f, b1r=0.f, b1i=0.f;
    for (int fb = 0; fb < 4; fb++){
      int m = ((fb*16)*hp) & 63;
      float twr = t64r[m], twi = t64i[m];
      for (int ff = 0; ff < 16; ff++){
        int f = fb*16 + ff;
        float sg = (f & 1) ? -1.f : 1.f;
        v4f Gr = *(const v4f*)&gr[f*36 + 4*g];
        v4f Gi = *(const v4f*)&gi[f*36 + 4*g];
        v4f pr = Gr*twr - Gi*twi;
        v4f pi = Gr*twi + Gi*twr;
        a0r += pr; a0i += pi;
        a1r += sg*pr; a1i += sg*pi;
        if (g == 0){
          float Tr = gr[f*36 + 32], Ti = gi[f*36 + 32];
          float prs = Tr*twr - Ti*twi, pis = Tr*twi + Ti*twr;
          b0r += prs; b0i += pis; b1r += sg*prs; b1i += sg*pis;
        }
        float nr = twr*stepr - twi*stepi, ni = twr*stepi + twi*stepr;
        twr = nr; twi = ni;
      }
    }
    #pragma unroll
    for (int j = 0; j < 4; j++){
      int k = 4*g + j;
      float ck = (k == 0) ? (1.f/64.f) : (2.f/64.f);
      ur[hp*36 + k] = a0r[j]*ck;       ui[hp*36 + k] = a0i[j]*ck;
      ur[(hp+32)*36 + k] = a1r[j]*ck;  ui[(hp+32)*36 + k] = a1i[j]*ck;
    }
    if (g == 0){
      ur[hp*36 + 32] = b0r*(1.f/64.f);      ui[hp*36 + 32] = b0i*(1.f/64.f);
      ur[(hp+32)*36 + 32] = b1r*(1.f/64.f); ui[(hp+32)*36 + 32] = b1i*(1.f/64.f);
    }
  }
  __syncthreads();
  {
    int h = tid & 63, wg = tid >> 6;
    v8f accL = (v8f)0.f, accH = (v8f)0.f, twr, twi, sr, si;
    #pragma unroll
    for (int j = 0; j < 8; j++){
      int wl = 8*wg + j;
      sr[j] = t64r[wl]; si[j] = t64i[wl];
      twr[j] = 1.f; twi[j] = 0.f;
    }
    float acc32 = 0.f;
    for (int kb = 0; kb < 8; kb++){
      v4f U4 = *(const v4f*)&ur[h*36 + 4*kb];
      v4f V4 = *(const v4f*)&ui[h*36 + 4*kb];
      #pragma unroll
      for (int e = 0; e < 4; e++){
        int k = 4*kb + e;
        float Ur = U4[e], Ui = V4[e];
        if (wg == 0) acc32 += (k & 1) ? -Ur : Ur;
        v8f p = Ur*twr, q = Ui*twi;
        accL += p - q;
        accH += p + q;
        v8f nr = twr*sr - twi*si;
        v8f ni = twr*si + twi*sr;
        twr = nr; twi = ni;
      }
    }
    {
      float Ur = ur[h*36 + 32], Ui = ui[h*36 + 32];
      if (wg == 0) acc32 += Ur;
      v8f p = Ur*twr, q = Ui*twi;
      accL += p - q;
      accH += p + q;
    }
    #pragma unroll
    for (int j = 0; j < 8; j++){
      int wl = 8*wg + j;
      sx2[h*65 + wl] = accL[j];
      if (wl == 0) sx2[h*65 + 32] = acc32;
      else         sx2[h*65 + 64 - wl] = accH[j];
    }
  }
  __syncthreads();
  {
    float bia = wb[c];
    #pragma unroll
    for (int it = 0; it < 8; it++){
      int idx = tid + it*256;           // 2048 pairs
      int h = idx >> 5, pw = idx & 31;
      int w0 = pw*2;
      size_t q = (size_t)plane*1024 + (size_t)(h >> 1)*32 + pw;
      float LL = ll[q];
      float LH = wnew[q] + bia;
      float HL = wnew[786432 + q] + bia;
      float HH = wnew[1572864 + q] + bia;
      float2 xc2 = *(const float2*)&xc[(size_t)plane*4096 + h*64 + w0];
      float v0, v1;
      if (!(h & 1)){ v0 = (LL + LH + HL + HH)*0.5f; v1 = (LL - LH + HL - HH)*0.5f; }
      else         { v0 = (LL + LH - HL - HH)*0.5f; v1 = (LL - LH - HL + HH)*0.5f; }
      sx2[h*65 + w0]     += 2.0f*xc2.x + v0;
      sx2[h*65 + w0 + 1] += 2.0f*xc2.y + v1;
    }
  }
  __syncthreads();
  {
    float wk[9];
    #pragma unroll
    for (int q = 0; q < 9; q++) wk[q] = dww[c*9 + q];
    float dbv = dwb[c];
    int w = tid & 63, st = tid >> 6;
    int h0 = st*16;
    bool wl_ok = (w > 0), wr_ok = (w < 63);
    float r0l, r0c, r0r, r1l, r1c, r1r;
    if (h0 > 0){
      r0l = wl_ok ? sx2[(h0-1)*65 + w-1] : 0.f;
      r0c = sx2[(h0-1)*65 + w];
      r0r = wr_ok ? sx2[(h0-1)*65 + w+1] : 0.f;
    } else { r0l = 0.f; r0c = 0.f; r0r = 0.f; }
    r1l = wl_ok ? sx2[h0*65 + w-1] : 0.f;
    r1c = sx2[h0*65 + w];
    r1r = wr_ok ? sx2[h0*65 + w+1] : 0.f;
    #pragma unroll
    for (int hh2 = 0; hh2 < 16; hh2++){
      int h = h0 + hh2;
      float r2l, r2c, r2r;
      if (h < 63){
        r2l = wl_ok ? sx2[(h+1)*65 + w-1] : 0.f;
        r2c = sx2[(h+1)*65 + w];
        r2r = wr_ok ? sx2[(h+1)*65 + w+1] : 0.f;
      } else { r2l = 0.f; r2c = 0.f; r2r = 0.f; }
      float acc = dbv + r0l*wk[0] + r0c*wk[1] + r0r*wk[2]
                      + r1l*wk[3] + r1c*wk[4] + r1r*wk[5]
                      + r2l*wk[6] + r2c*wk[7] + r2r*wk[8];
      scratch[h*65 + w] = acc / (1.f + __expf(-acc));
      r0l = r1l; r0c = r1c; r0r = r1r;
      r1l = r2l; r1c = r2c; r1r = r2r;
    }
  }
  __syncthreads();
  float* abp = ab + (size_t)plane*4096;
  float* aTp = aT + (size_t)plane*4096;
  for (int p = tid; p < 4096; p += 256){
    abp[p] = scratch[(p >> 6)*65 + (p & 63)];
    aTp[p] = scratch[(p & 63)*65 + (p >> 6)];
  }
}

// ------------------------------------------------ K10: x_proj; wave-split GEMM
__global__ __launch_bounds__(256) void k_xproj(const float* __restrict__ ab,
    const float* __restrict__ aT, const float* __restrict__ xpw,
    float* __restrict__ Bsb, float* __restrict__ Csb, float* __restrict__ dlsb,
    float* __restrict__ xsb){
  int bid = blockIdx.x;
  int s = bid & 63; int k = (bid >> 6) & 3; int b = bid >> 8;
  int tid = threadIdx.x;
  __shared__ float als[96][65];
  __shared__ float dls[6][64];
  int l0 = s << 6;
  const float* src = (k & 1) ? aT : ab;
  bool rev = (k >= 2);
  int i = tid & 63, wg = tid >> 6;
  const float* wr[10];
  #pragma unroll
  for (int r = 0; r < 10; r++){
    int cp = wg + 4*r; if (cp > 37) cp = 37;
    int off = __builtin_amdgcn_readfirstlane((k*38 + cp)*192);
    wr[r] = xpw + off;
  }
  float acc[10];
  #pragma unroll
  for (int r = 0; r < 10; r++) acc[r] = 0.f;
  size_t xbase = ((size_t)(b*4 + k)*4096 + l0)*192;
  #pragma unroll
  for (int half = 0; half < 2; half++){
    int d0 = half*96;
    for (int idx = tid; idx < 1536; idx += 256){
      int d = idx >> 4, i4 = idx & 15;
      const float* rowp = src + ((size_t)b*192 + d0 + d)*4096;
      if (!rev){
        float4 v = *(const float4*)&rowp[l0 + 4*i4];
        als[d][4*i4+0] = v.x; als[d][4*i4+1] = v.y;
        als[d][4*i4+2] = v.z; als[d][4*i4+3] = v.w;
      } else {
        float4 v = *(const float4*)&rowp[4092 - l0 - 4*i4];
        als[d][4*i4+0] = v.w; als[d][4*i4+1] = v.z;
        als[d][4*i4+2] = v.y; als[d][4*i4+3] = v.x;
      }
    }
    __syncthreads();
    for (int d = 0; d < 96; d++){
      float v = als[d][i];
      #pragma unroll
      for (int r = 0; r < 10; r++) acc[r] += v*wr[r][d0 + d];
    }
    for (int idx = tid; idx < 1536; idx += 256){
      int ii = idx / 24, cc = (idx - (idx/24)*24)*4;
      float4 v;
      v.x = als[cc+0][ii]; v.y = als[cc+1][ii];
      v.z = als[cc+2][ii]; v.w = als[cc+3][ii];
      *(float4*)&xsb[xbase + (size_t)ii*192 + d0 + cc] = v;
    }
    __syncthreads();
  }
  #pragma unroll
  for (int r = 0; r < 10; r++){
    int cp = wg + 4*r;
    if (cp > 37) continue;
    if (cp < 6) dls[cp][i] = acc[r];
    else if (cp < 22) Bsb[((size_t)(b*4 + k)*16 + (cp - 6 ))*4096 + l0 + i] = acc[r];
    else              Csb[((size_t)(b*4 + k)*16 + (cp - 22))*4096 + l0 + i] = acc[r];
  }
  __syncthreads();
  size_t dbase = (size_t)((b*4 + k)*64 + s)*384;
  for (int j = tid; j < 384; j += 256){
    int ii = j/6, r = j - ii*6;
    dlsb[dbase + j] = dls[r][ii];
  }
}

// ------------------------------------------------ K11: scan phase A — v2: log-depth e1-power
// tree (p2/p4/p8) replaces the 16-step serial e-chain; all 16 P/Q updates become
// independent. Same op count, critical path 16 -> ~6.
__global__ __launch_bounds__(192) void k_scanA(const float* __restrict__ xsb,
    const float* __restrict__ dlsb, const float* __restrict__ Bsb,
    const float* __restrict__ dtw, const float* __restrict__ dtb,
    const float* __restrict__ alog, float* __restrict__ Pb, float* __restrict__ Qb){
  int bid = blockIdx.x; int s = bid & 63; int k = (bid >> 6) & 3; int b = bid >> 8;
  int c = threadIdx.x; int bk = b*4 + k;
  __shared__ float sdl[384];
  __shared__ float sB[16][64];
  size_t dbase = (size_t)(bk*64 + s)*384;
  for (int j = c; j < 384; j += 192) sdl[j] = dlsb[dbase + j];
  for (int j = c; j < 1024; j += 192){ int n = j >> 6, i = j & 63;
    sB[n][i] = Bsb[((size_t)bk*16 + n)*4096 + (s << 6) + i]; }
  __syncthreads();
  float A[16], P[16], Q[16];
  const float* arow = alog + ((size_t)k*192 + c)*16;
  bool fast = true;
  #pragma unroll
  for (int n = 0; n < 16; n++){
    A[n] = -__expf(arow[n]); P[n] = 1.f; Q[n] = 0.f;
    if (fabsf(A[n] + (float)(n+1)) > 1e-3f) fast = false;
  }
  float dw[6];
  #pragma unroll
  for (int r = 0; r < 6; r++) dw[r] = dtw[((size_t)k*192 + c)*6 + r];
  float db = dtb[k*192 + c];
  const float* xrow = xsb + ((size_t)bk*4096 + (s << 6))*192 + c;
  if (fast){
    for (int i = 0; i < 64; i++){
      float u = xrow[(size_t)i*192];
      float acc = db;
      #pragma unroll
      for (int r = 0; r < 6; r++) acc += sdl[i*6 + r]*dw[r];
      float ec = __expf(fminf(acc, 80.f));
      float e1 = __builtin_amdgcn_rcpf(1.f + ec);
      float du = __logf(1.f + ec)*u;
      float p2 = e1*e1, p4 = p2*p2, p8 = p4*p4;
      float E[16];
      E[0]=e1;      E[1]=p2;      E[2]=p2*e1;   E[3]=p4;
      E[4]=p4*e1;   E[5]=p4*p2;   E[6]=E[5]*e1; E[7]=p8;
      E[8]=p8*e1;   E[9]=p8*p2;   E[10]=E[9]*e1; E[11]=p8*p4;
      E[12]=E[11]*e1; E[13]=E[11]*p2; E[14]=E[13]*e1; E[15]=p8*p8;
      #pragma unroll
      for (int n = 0; n < 16; n++){
        P[n] *= E[n];
        Q[n] = Q[n]*E[n] + du*sB[n][i];
      }
    }
  } else {
    for (int i = 0; i < 64; i++){
      float u = xrow[(size_t)i*192];
      float acc = db;
      #pragma unroll
      for (int r = 0; r < 6; r++) acc += sdl[i*6 + r]*dw[r];
      float ec = __expf(fminf(acc, 80.f));
      float dl = __logf(1.f + ec);
      float du = dl*u;
      #pragma unroll
      for (int n = 0; n < 16; n++){
        float e = __expf(dl*A[n]);
        P[n] *= e;
        Q[n] = Q[n]*e + du*sB[n][i];
      }
    }
  }
  size_t pbase = ((size_t)(bk*64 + s)*16)*192 + c;
  #pragma unroll
  for (int n = 0; n < 16; n++){ Pb[pbase + (size_t)n*192] = P[n]; Qb[pbase + (size_t)n*192] = Q[n]; }
}

// ------------------------------------------------ K12: scan phase B (hin in-place over Pb)
__global__ __launch_bounds__(256) void k_scanB(float* __restrict__ Pb,
    const float* __restrict__ Qb){
  int id = blockIdx.x*256 + threadIdx.x;
  int c = id % 192; int rest = id / 192; int n = rest % 16; int bk = rest / 16;
  float h = 0.f;
  for (int s = 0; s < 64; s++){
    size_t o = (((size_t)bk*64 + s)*16 + n)*192 + c;
    float P = Pb[o], Q = Qb[o];
    Pb[o] = h;
    h = P*h + Q;
  }
}

// ------------------------------------------------ K13a: scan phase C — v2: log-depth e1-power
// tree + 4-partial y reduction (critical path per i: ~32 -> ~10 dependent ops).
__global__ __launch_bounds__(192) void k_scanC_buf(const float* __restrict__ xsb,
    const float* __restrict__ dlsb, const float* __restrict__ Bsb, const float* __restrict__ Csb,
    const float* __restrict__ hinb, const float* __restrict__ dtw, const float* __restrict__ dtb,
    const float* __restrict__ alog, const float* __restrict__ Dsp, float* __restrict__ Y){
  int bid = blockIdx.x; int s = bid & 63; int k = (bid >> 6) & 3; int b = bid >> 8;
  int c = threadIdx.x; int bk = b*4 + k;
  __shared__ float sdl[384];
  __shared__ float sB[16][64];
  __shared__ float sC[16][64];
  size_t dbase = (size_t)(bk*64 + s)*384;
  for (int j = c; j < 384; j += 192) sdl[j] = dlsb[dbase + j];
  for (int j = c; j < 1024; j += 192){ int n = j >> 6, i = j & 63;
    size_t o = ((size_t)bk*16 + n)*4096 + (s << 6) + i;
    sB[n][i] = Bsb[o]; sC[n][i] = Csb[o]; }
  __syncthreads();
  float A[16], h[16];
  const float* arow = alog + ((size_t)k*192 + c)*16;
  bool fast = true;
  #pragma unroll
  for (int n = 0; n < 16; n++){
    A[n] = -__expf(arow[n]);
    if (fabsf(A[n] + (float)(n+1)) > 1e-3f) fast = false;
  }
  size_t hbase = ((size_t)(bk*64 + s)*16)*192 + c;
  #pragma unroll
  for (int n = 0; n < 16; n++) h[n] = hinb[hbase + (size_t)n*192];
  float dw[6];
  #pragma unroll
  for (int r = 0; r < 6; r++) dw[r] = dtw[((size_t)k*192 + c)*6 + r];
  float db = dtb[k*192 + c];
  float Dc = Dsp[k*192 + c];
  const float* xrow = xsb + ((size_t)bk*4096 + (s << 6))*192 + c;
  float* Yk = Y + (((size_t)bk*4096 + (s << 6))*192) + c;
  if (fast){
    for (int i = 0; i < 64; i++){
      float u = xrow[(size_t)i*192];
      float acc = db;
      #pragma unroll
      for (int r = 0; r < 6; r++) acc += sdl[i*6 + r]*dw[r];
      float ec = __expf(fminf(acc, 80.f));
      float e1 = __builtin_amdgcn_rcpf(1.f + ec);
      float du = __logf(1.f + ec)*u;
      float p2 = e1*e1, p4 = p2*p2, p8 = p4*p4;
      float E[16];
      E[0]=e1;      E[1]=p2;      E[2]=p2*e1;   E[3]=p4;
      E[4]=p4*e1;   E[5]=p4*p2;   E[6]=E[5]*e1; E[7]=p8;
      E[8]=p8*e1;   E[9]=p8*p2;   E[10]=E[9]*e1; E[11]=p8*p4;
      E[12]=E[11]*e1; E[13]=E[11]*p2; E[14]=E[13]*e1; E[15]=p8*p8;
      float y0 = 0.f, y1 = 0.f, y2 = 0.f, y3 = 0.f;
      #pragma unroll
      for (int n = 0; n < 16; n++){
        h[n] = h[n]*E[n] + du*sB[n][i];
        float t = h[n]*sC[n][i];
        if ((n & 3) == 0) y0 += t;
        else if ((n & 3) == 1) y1 += t;
        else if ((n & 3) == 2) y2 += t;
        else y3 += t;
      }
      Yk[(size_t)i*192] = ((y0 + y1) + (y2 + y3)) + u*Dc;
    }
  } else {
    for (int i = 0; i < 64; i++){
      float u = xrow[(size_t)i*192];
      float acc = db;
      #pragma unroll
      for (int r = 0; r < 6; r++) acc += sdl[i*6 + r]*dw[r];
      float ec = __expf(fminf(acc, 80.f));
      float dl = __logf(1.f + ec);
      float du = dl*u;
      float y = 0.f;
      #pragma unroll
      for (int n = 0; n < 16; n++){
        float e = __expf(dl*A[n]);
        h[n] = h[n]*e + du*sB[n][i];
        y += h[n]*sC[n][i];
      }
      Yk[(size_t)i*192] = y + u*Dc;
    }
  }
}

// ------------------------------------------------ K13b: scan phase C — atomic fallback
__global__ __launch_bounds__(192) void k_scanC_atom(const float* __restrict__ xsb,
    const float* __restrict__ dlsb, const float* __restrict__ Bsb, const float* __restrict__ Csb,
    const float* __restrict__ hinb, const float* __restrict__ dtw, const float* __restrict__ dtb,
    const float* __restrict__ alog, const float* __restrict__ Dsp, float* __restrict__ yb){
  int bid = blockIdx.x; int s = bid & 63; int k = (bid >> 6) & 3; int b = bid >> 8;
  int c = threadIdx.x; int bk = b*4 + k;
  __shared__ float sdl[384];
  __shared__ float sB[16][64];
  __shared__ float sC[16][64];
  size_t dbase = (size_t)(bk*64 + s)*384;
  for (int j = c; j < 384; j += 192) sdl[j] = dlsb[dbase + j];
  for (int j = c; j < 1024; j += 192){ int n = j >> 6, i = j & 63;
    size_t o = ((size_t)bk*16 + n)*4096 + (s << 6) + i;
    sB[n][i] = Bsb[o]; sC[n][i] = Csb[o]; }
  __syncthreads();
  float A[16], h[16];
  const float* arow = alog + ((size_t)k*192 + c)*16;
  bool fast = true;
  #pragma unroll
  for (int n = 0; n < 16; n++){
    A[n] = -__expf(arow[n]);
    if (fabsf(A[n] + (float)(n+1)) > 1e-3f) fast = false;
  }
  size_t hbase = ((size_t)(bk*64 + s)*16)*192 + c;
  #pragma unroll
  for (int n = 0; n < 16; n++) h[n] = hinb[hbase + (size_t)n*192];
  float dw[6];
  #pragma unroll
  for (int r = 0; r < 6; r++) dw[r] = dtw[((size_t)k*192 + c)*6 + r];
  float db = dtb[k*192 + c];
  float Dc = Dsp[k*192 + c];
  const float* xrow = xsb + ((size_t)bk*4096 + (s << 6))*192 + c;
  int p0, pst;
  if (k == 0){ p0 = s << 6;        pst = 1;  }
  else if (k == 1){ p0 = s;        pst = 64; }
  else if (k == 2){ p0 = 4095 - (s << 6); pst = -1; }
  else { p0 = 4095 - s;            pst = -64; }
  for (int i = 0; i < 64; i++){
    float u = xrow[(size_t)i*192];
    float acc = db;
    #pragma unroll
    for (int r = 0; r < 6; r++) acc += sdl[i*6 + r]*dw[r];
    float ec = __expf(fminf(acc, 80.f));
    float dl = __logf(1.f + ec);
    float du = dl*u;
    float y = 0.f;
    if (fast){
      float e1 = __builtin_amdgcn_rcpf(1.f + ec);
      float e = 1.f;
      #pragma unroll
      for (int n = 0; n < 16; n++){
        e *= e1;
        h[n] = h[n]*e + du*sB[n][i];
        y += h[n]*sC[n][i];
      }
    } else {
      #pragma unroll
      for (int n = 0; n < 16; n++){
        float e = __expf(dl*A[n]);
        h[n] = h[n]*e + du*sB[n][i];
        y += h[n]*sC[n][i];
      }
    }
    y += u*Dc;
    atomicAdd(&yb[((size_t)b*4096 + p0 + pst*i)*192 + c], y);
  }
}

// ------------------------------------------------ K14b: symmetry enhance (atomic path)
__global__ __launch_bounds__(256) void k_enh(const float* __restrict__ yb,
    const float* __restrict__ symw, float* __restrict__ yfb){
  int id = blockIdx.x*256 + threadIdx.x;
  int c = id % 192; int rest = id / 192; int l = rest & 4095; int b = rest >> 12;
  int w = l & 63; int lr = (l | 63) - w;
  float v  = yb[id];
  float vr = yb[(((size_t)b << 12) + lr)*192 + c];
  float wg = 1.f/(1.f + __expf(-symw[0]));
  float enh = v*(1.f - wg) + 0.5f*(v + vr)*wg;
  yfb[id] = v + 0.2f*enh;
}

// ------------------------------------------------ K15a (fused, bigws): gather scan-order Y + enh + LN + out_proj
// v5: og merged — ONE block per (lt,b) tile computes all 96 outputs (acc[12]/thread),
//     halving the duplicated Y-gather + zT reads. opw staged in four 48-c quarters
//     through a padded 19.2 KB buffer; LDS ~46 KB => 3 blocks/CU; grid 512 (all
//     resident, no tail). Gather/enh/LN phases identical to R9.
__global__ __launch_bounds__(256) void k_final_comb(const float* __restrict__ Y,
    const float* __restrict__ symw, const float* __restrict__ zT,
    const float* __restrict__ g, const float* __restrict__ bta,
    const float* __restrict__ opw, const float* __restrict__ x, float* __restrict__ out){
  int lt = blockIdx.x & 127; int b = blockIdx.x >> 7;
  int h = lt >> 1, wsel = lt & 1;
  __shared__ float sv[32][193];
  __shared__ float wtb[48*100];     // quarter: [48 c][96 o], stride 100 (pad)
  __shared__ float sg[192], sb2[192];
  __shared__ float smu[32], srs[32];
  __shared__ int lmap[32];
  int tid = threadIdx.x;
  const size_t S = (size_t)4096*192;
  float wg = 1.f/(1.f + __expf(-symw[0]));
  if (tid < 32){
    int r = tid;
    int w = (r < 16) ? (wsel*16 + r) : (63 - wsel*16 - (r - 16));
    lmap[r] = h*64 + w;
  }
  for (int idx = tid; idx < 1536; idx += 256){
    int r = idx / 48, c4 = (idx - (idx/48)*48)*4;
    int w = (r < 16) ? (wsel*16 + r) : (63 - wsel*16 - (r - 16));
    int l = h*64 + w;
    int p1 = (w << 6) | h;
    size_t base = (size_t)(b*4)*S + c4;
    float4 v0 = *(const float4*)&Y[base + (size_t)l*192];
    float4 v1 = *(const float4*)&Y[base + S + (size_t)p1*192];
    float4 v2 = *(const float4*)&Y[base + 2*S + (size_t)(4095 - l)*192];
    float4 v3 = *(const float4*)&Y[base + 3*S + (size_t)(4095 - p1)*192];
    sv[r][c4+0] = v0.x + v1.x + v2.x + v3.x;
    sv[r][c4+1] = v0.y + v1.y + v2.y + v3.y;
    sv[r][c4+2] = v0.z + v1.z + v2.z + v3.z;
    sv[r][c4+3] = v0.w + v1.w + v2.w + v3.w;
  }
  if (tid < 192){ sg[tid] = g[tid]; sb2[tid] = bta[tid]; }
  __syncthreads();
  float yreg[24];
  #pragma unroll
  for (int t = 0; t < 24; t++){
    int idx = tid + t*256;
    int r = idx / 192, cc = idx - r*192;
    int rp = (r < 16) ? r + 16 : r - 16;
    float v = sv[r][cc], vp = sv[rp][cc];
    float enh = v*(1.f - wg) + 0.5f*(v + vp)*wg;
    yreg[t] = v + 0.2f*enh;
  }
  __syncthreads();
  #pragma unroll
  for (int t = 0; t < 24; t++){
    int idx = tid + t*256;
    int r = idx / 192, cc = idx - r*192;
    sv[r][cc] = yreg[t];
  }
  __syncthreads();
  if (tid < 32){
    float s1 = 0.f, s2 = 0.f;
    for (int c = 0; c < 192; c++){ float v = sv[tid][c]; s1 += v; s2 += v*v; }
    float mu = s1*(1.0f/192.0f);
    smu[tid] = mu; srs[tid] = rsqrtf(s2*(1.0f/192.0f) - mu*mu + 1e-5f);
  }
  __syncthreads();
  for (int idx = tid; idx < 6144; idx += 256){ int l = idx & 31, c = idx >> 5;
    float zv = zT[((size_t)b*192 + c)*4096 + lmap[l]];
    float v = sv[l][c];
    float yn = (v - smu[l])*srs[l]*sg[c] + sb2[c];
    sv[l][c] = yn * (zv/(1.f + __expf(-zv)));
  }
  int l = tid & 31, grp = tid >> 5;   // 8 groups x 12 outputs = 96
  float acc[12];
  #pragma unroll
  for (int j = 0; j < 12; j++) acc[j] = 0.f;
  #pragma unroll
  for (int q = 0; q < 4; q++){
    __syncthreads();
    // stage quarter q: c' in [0,48), all 96 outputs; coalesced opw reads
    for (int idx = tid; idx < 4608; idx += 256){
      int cc = idx % 48, o = idx / 48;
      wtb[cc*100 + o] = opw[(size_t)o*192 + q*48 + cc];
    }
    __syncthreads();
    for (int c = 0; c < 48; c++){
      float svv = sv[l][q*48 + c];
      const float* wr = &wtb[c*100 + grp*12];
      #pragma unroll
      for (int j = 0; j < 12; j += 4){
        float4 w4 = *(const float4*)&wr[j];
        acc[j]   += svv*w4.x; acc[j+1] += svv*w4.y;
        acc[j+2] += svv*w4.z; acc[j+3] += svv*w4.w;
      }
    }
  }
  size_t ob = ((size_t)b*4096 + lmap[l])*96 + grp*12;
  #pragma unroll
  for (int j = 0; j < 12; j += 4){
    float4 x4 = *(const float4*)&x[ob + j];
    float4 v2;
    v2.x = acc[j]   + x4.x; v2.y = acc[j+1] + x4.y;
    v2.z = acc[j+2] + x4.z; v2.w = acc[j+3] + x4.w;
    *(float4*)&out[ob + j] = v2;
  }
}

// ------------------------------------------------ K15b: fallback
__global__ __launch_bounds__(256) void k_final(const float* __restrict__ yf,
    const float* __restrict__ zT, const float* __restrict__ g, const float* __restrict__ bta,
    const float* __restrict__ opw, const float* __restrict__ x, float* __restrict__ out){
  int og = blockIdx.x & 1; int lt = (blockIdx.x >> 1) & 127; int b = blockIdx.x >> 8;
  int l0 = lt << 5;
  __shared__ float sv[32][193];
  __shared__ float wt[192*48];
  __shared__ float sg[192], sb2[192];
  __shared__ float smu[32], srs[32];
  int tid = threadIdx.x;
  for (int idx = tid; idx < 6144; idx += 256){ int r = idx/192, c = idx - r*192;
    sv[r][c] = yf[((size_t)b*4096 + l0 + r)*192 + c]; }
  if (tid < 192){ sg[tid] = g[tid]; sb2[tid] = bta[tid]; }
  int o0 = og*48;
  for (int idx = tid; idx < 9216; idx += 256){ int o = idx % 48, c = idx/48;
    wt[c*48 + o] = opw[(size_t)(o0 + o)*192 + c]; }
  __syncthreads();
  if (tid < 32){
    float s1 = 0.f, s2 = 0.f;
    for (int c = 0; c < 192; c++){ float v = sv[tid][c]; s1 += v; s2 += v*v; }
    float mu = s1*(1.0f/192.0f);
    smu[tid] = mu; srs[tid] = rsqrtf(s2*(1.0f/192.0f) - mu*mu + 1e-5f);
  }
  __syncthreads();
  for (int idx = tid; idx < 6144; idx += 256){ int l = idx & 31, c = idx >> 5;
    float zv = zT[((size_t)b*192 + c)*4096 + l0 + l];
    float v = sv[l][c];
    float yn = (v - smu[l])*srs[l]*sg[c] + sb2[c];
    sv[l][c] = yn * (zv/(1.f + __expf(-zv)));
  }
  __syncthreads();
  int l = tid & 31, grp = tid >> 5;
  float acc[6];
  #pragma unroll
  for (int j = 0; j < 6; j++) acc[j] = 0.f;
  for (int c = 0; c < 192; c++){
    float svv = sv[l][c];
    const float* wr = &wt[c*48 + grp*6];
    #pragma unroll
    for (int j = 0; j < 6; j += 2){
      float2 w2 = *(const float2*)&wr[j];
      acc[j]   += svv*w2.x; acc[j+1] += svv*w2.y;
    }
  }
  size_t ob = ((size_t)b*4096 + l0 + l)*96 + o0 + grp*6;
  #pragma unroll
  for (int j = 0; j < 6; j++) acc[j] += x[ob + j];
  #pragma unroll
  for (int j = 0; j < 6; j += 2){
    float2 v2; v2.x = acc[j]; v2.y = acc[j+1];
    *(float2*)&out[ob + j] = v2;
  }
}

// ================================================================ host
extern "C" void kernel_launch(void* const* d_in, const int* in_sizes, int n_in,
                              void* d_out, int out_size, void* d_ws, size_t ws_size,
                              hipStream_t stream){
  (void)in_sizes; (void)n_in; (void)out_size;
  const float* ix   = (const float*)d_in[0];
  const float* ipw  = (const float*)d_in[1];
  const float* fw1  = (const float*)d_in[2];
  const float* fb1  = (const float*)d_in[3];
  const float* fw2  = (const float*)d_in[4];
  const float* fb2  = (const float*)d_in[5];
  const float* ww   = (const float*)d_in[6];
  const float* wb   = (const float*)d_in[7];
  const float* dww  = (const float*)d_in[8];
  const float* dwb  = (const float*)d_in[9];
  const float* symw = (const float*)d_in[10];
  const float* xpw  = (const float*)d_in[11];
  const float* dtw  = (const float*)d_in[12];
  const float* dtb  = (const float*)d_in[13];
  const float* alog = (const float*)d_in[14];
  const float* Dsp  = (const float*)d_in[15];
  const float* ong  = (const float*)d_in[16];
  const float* onb  = (const float*)d_in[17];
  const float* opw  = (const float*)d_in[18];
  const float* rmsw = (const float*)d_in[19];

  float* W = (float*)d_ws;
  const size_t SZ_BLC = 3145728, SZ_F = 1622016, SZ_H = 786432;
  float* zT  = W;
  float* ab  = zT + SZ_BLC;
  float* R0  = ab + SZ_BLC;
  // phase 1
  float* xc    = R0;
  float* fre   = xc  + SZ_BLC;
  float* fim   = fre + SZ_F;
  float* fab   = fim + SZ_F;
  float* mb    = fab + SZ_F;
  float* llb   = mb  + SZ_F;
  float* lhb   = llb + SZ_H;
  float* wnew  = lhb + 3*SZ_H;
  unsigned short* wqb2 = (unsigned short*)(wnew + 2359296);
  unsigned short* lhT  = wqb2 + 331776;   // 12 img x 1024 pix x 192 ic, bf16 (2.36M shorts)
  // phase 2
  float* Bsb  = R0;
  float* Csb  = Bsb + 1048576;
  float* dlsb = Csb + 1048576;
  float* xsb  = dlsb + 393216;
  float* Pb   = xsb + 12582912;
  float* aT   = Pb;
  float* Qb   = Pb + SZ_BLC;
  float* Yb   = Qb;                  // scan-order Y [bk][iscan][c]
  float* ybA  = Qb + SZ_BLC;
  float* yfb  = xsb;

  const size_t NEED_BIG = (size_t)(6291456 + 30801920) * 4;
  bool bigws = (ws_size >= NEED_BIG);

  hipLaunchKernelGGL(k_rms_inproj, dim3(2048),   dim3(256), 0, stream, ix, rmsw, ipw, xc, zT);
  hipLaunchKernelGGL(k_dft_fwd,    dim3(4*192),  dim3(256), 0, stream, xc, fre, fim, fab,
                     llb, lhb, lhb + SZ_H, lhb + 2*SZ_H);
  hipLaunchKernelGGL(k_cvt_w,      dim3(1296),   dim3(256), 0, stream, ww, wqb2);
  hipLaunchKernelGGL(k_prep_lhT,   dim3(1152),   dim3(256), 0, stream, lhb, lhT);
  hipLaunchKernelGGL(k_cmix1,      dim3(864),    dim3(256), 0, stream, fab, fw1, fb1, mb);
  hipLaunchKernelGGL(k_cmix2,      dim3(864),    dim3(256), 0, stream, mb, fw2, fb2, fre, fim, fab);
  hipLaunchKernelGGL(k_wconv_mfma, dim3(576),    dim3(256), 0, stream, lhT, wqb2, wnew);
  hipLaunchKernelGGL(k_ifwd,       dim3(768),    dim3(256), 0, stream, fre, fim, xc, llb, wnew, wb, dww, dwb, ab, aT);
  hipLaunchKernelGGL(k_xproj,      dim3(1024),   dim3(256), 0, stream, ab, aT, xpw, Bsb, Csb, dlsb, xsb);
  hipLaunchKernelGGL(k_scanA,      dim3(1024),   dim3(192), 0, stream, xsb, dlsb, Bsb, dtw, dtb, alog, Pb, Qb);
  hipLaunchKernelGGL(k_scanB,      dim3(192),    dim3(256), 0, stream, Pb, Qb);
  if (bigws){
    hipLaunchKernelGGL(k_scanC_buf,  dim3(1024), dim3(192), 0, stream, xsb, dlsb, Bsb, Csb, Pb, dtw, dtb, alog, Dsp, Yb);
    hipLaunchKernelGGL(k_final_comb, dim3(512),  dim3(256), 0, stream, Yb, symw, zT, ong, onb, opw, ix, (float*)d_out);
  } else {
    hipLaunchKernelGGL(k_zero,       dim3(12288), dim3(256), 0, stream, ybA, (int)SZ_BLC);
    hipLaunchKernelGGL(k_scanC_atom, dim3(1024),  dim3(192), 0, stream, xsb, dlsb, Bsb, Csb, Pb, dtw, dtb, alog, Dsp, ybA);
    hipLaunchKernelGGL(k_enh,        dim3(12288), dim3(256), 0, stream, ybA, symw, yfb);
    hipLaunchKernelGGL(k_final,      dim3(1024),  dim3(256), 0, stream, yfb, zT, ong, onb, opw, ix, (float*)d_out);
  }
}

// Round 11
// 592.206 us; speedup vs baseline: 1.7711x; 1.7711x over previous
//
#include <hip/hip_runtime.h>
#include <hip/hip_bf16.h>

#define CI 192
#define LL_ 4096

typedef __bf16 v8bf __attribute__((ext_vector_type(8)));
typedef float  v4f  __attribute__((ext_vector_type(4)));
typedef float  v8f  __attribute__((ext_vector_type(8)));
typedef unsigned short v8us __attribute__((ext_vector_type(8)));

__device__ __forceinline__ unsigned short f2bf(float v){
  unsigned int u = __float_as_uint(v);
  return (unsigned short)((u + 0x7FFFu + ((u >> 16) & 1u)) >> 16);
}

__global__ __launch_bounds__(256) void k_zero(float* __restrict__ p, int n){
  int i = blockIdx.x*256 + threadIdx.x;
  if (i < n) p[i] = 0.f;
}

// ------------------------------------------------ K1: RMSNorm + in_proj (tiled GEMM, 48-o tiles)
__global__ __launch_bounds__(256) void k_rms_inproj(const float* __restrict__ x,
    const float* __restrict__ rmsw, const float* __restrict__ ipw,
    float* __restrict__ xc, float* __restrict__ zT){
  int og = blockIdx.x & 7; int lt = (blockIdx.x >> 3) & 63; int b = blockIdx.x >> 9;
  int l0 = lt << 6;
  __shared__ float xt[64][97];
  __shared__ float wt[96*48];
  __shared__ float rr[64];
  __shared__ float rw[96];
  int tid = threadIdx.x;
  for (int idx = tid; idx < 6144; idx += 256){ int r = idx/96, d = idx - r*96;
    xt[r][d] = x[((size_t)b*4096 + l0 + r)*96 + d]; }
  if (tid < 96) rw[tid] = rmsw[tid];
  int o0 = og*48;
  for (int idx = tid; idx < 4608; idx += 256){ int o = idx%48, d = idx/48;
    wt[d*48 + o] = ipw[(size_t)(o0 + o)*96 + d]; }
  __syncthreads();
  if (tid < 64){
    float s = 0.f;
    for (int d = 0; d < 96; d++){ float v = xt[tid][d]; s += v*v; }
    rr[tid] = rsqrtf(s*(1.0f/96.0f) + 1e-5f);
  }
  __syncthreads();
  for (int idx = tid; idx < 6144; idx += 256){ int r = idx/96, d = idx - r*96;
    xt[r][d] *= rr[r]*rw[d]; }
  __syncthreads();
  int l = tid & 63, grp = tid >> 6;
  float acc[12];
  #pragma unroll
  for (int j = 0; j < 12; j++) acc[j] = 0.f;
  for (int d = 0; d < 96; d++){
    float xv = xt[l][d];
    const float* wr = &wt[d*48 + grp*12];
    #pragma unroll
    for (int j = 0; j < 12; j += 4){
      float4 w4 = *(const float4*)&wr[j];
      acc[j]   += xv*w4.x; acc[j+1] += xv*w4.y;
      acc[j+2] += xv*w4.z; acc[j+3] += xv*w4.w;
    }
  }
  #pragma unroll
  for (int j = 0; j < 12; j++){
    int o = o0 + grp*12 + j;
    if (o < 192) xc[((size_t)b*192 + o)*4096 + l0 + l] = acc[j];
    else         zT[((size_t)b*192 + (o-192))*4096 + l0 + l] = acc[j];
  }
}

// ------------------------------------------------ K2: forward rfft2 (ortho) + fused Haar DWT
__global__ __launch_bounds__(256) void k_dft_fwd(const float* __restrict__ xc,
    float* __restrict__ fre, float* __restrict__ fim, float* __restrict__ fab,
    float* __restrict__ ll, float* __restrict__ lh, float* __restrict__ hl, float* __restrict__ hh){
  int plane = blockIdx.x;
  __shared__ float sxT[64*65];
  __shared__ float t1r[64*34], t1i[64*34];
  __shared__ float tabr[16], tabi[16];
  __shared__ float ct64[64], st64[64];
  int tid = threadIdx.x;
  const float* X = xc + (size_t)plane*4096;
  for (int i = tid; i < 4096; i += 256){ int h = i >> 6, w = i & 63; sxT[w*65 + h] = X[i]; }
  if (tid < 16){ tabr[tid] = cospif((float)tid/8.0f); tabi[tid] = -sinpif((float)tid/8.0f); }
  if (tid < 64){ ct64[tid] = cospif((float)tid/32.0f); st64[tid] = sinpif((float)tid/32.0f); }
  __syncthreads();
  {
    size_t qbase = (size_t)plane*1024;
    for (int idx = tid; idx < 1024; idx += 256){
      int y2 = idx >> 5, x2 = idx & 31;
      float a_ = sxT[(2*x2)*65 + 2*y2],     b_ = sxT[(2*x2+1)*65 + 2*y2];
      float c_ = sxT[(2*x2)*65 + 2*y2+1],   d_ = sxT[(2*x2+1)*65 + 2*y2+1];
      ll[qbase + idx] = (a_+b_+c_+d_)*0.5f; lh[qbase + idx] = (a_-b_+c_-d_)*0.5f;
      hl[qbase + idx] = (a_+b_-c_-d_)*0.5f; hh[qbase + idx] = (a_-b_-c_+d_)*0.5f;
    }
  }
  {
    int hp = tid & 31, g = tid >> 5;
    float a0r[4], a0i[4], a1r[4], a1i[4];
    #pragma unroll
    for (int j = 0; j < 4; j++){ a0r[j]=0.f; a0i[j]=0.f; a1r[j]=0.f; a1i[j]=0.f; }
    float s32_0 = 0.f, s32_1 = 0.f;
    for (int w = 0; w < 64; w++){
      float xv0 = sxT[w*65 + hp];
      float xv1 = sxT[w*65 + hp + 32];
      int m0 = (w*g) & 15;
      float twr = tabr[m0], twi = tabi[m0];
      int ms = w & 15;
      float str = tabr[ms], sti = tabi[ms];
      #pragma unroll
      for (int j = 0; j < 4; j++){
        a0r[j] += xv0*twr; a0i[j] += xv0*twi;
        a1r[j] += xv1*twr; a1i[j] += xv1*twi;
        float nr = twr*str - twi*sti;
        float ni = twr*sti + twi*str;
        twr = nr; twi = ni;
      }
      if (g == 0){ float sg = (w & 1) ? -1.f : 1.f; s32_0 += xv0*sg; s32_1 += xv1*sg; }
    }
    #pragma unroll
    for (int j = 0; j < 4; j++){
      int k = 4*g + j;
      t1r[hp*34 + k] = a0r[j];        t1i[hp*34 + k] = a0i[j];
      t1r[(hp+32)*34 + k] = a1r[j];   t1i[(hp+32)*34 + k] = a1i[j];
    }
    if (g == 0){
      t1r[hp*34 + 32] = s32_0;      t1i[hp*34 + 32] = 0.f;
      t1r[(hp+32)*34 + 32] = s32_1; t1i[(hp+32)*34 + 32] = 0.f;
    }
  }
  __syncthreads();
  {
    int fp = tid & 31, g = tid >> 5;
    float stepr = cospif((float)fp/32.0f), stepi = -sinpif((float)fp/32.0f);
    float a0r[4], a0i[4], a1r[4], a1i[4];
    #pragma unroll
    for (int j = 0; j < 4; j++){ a0r[j]=0.f; a0i[j]=0.f; a1r[j]=0.f; a1i[j]=0.f; }
    float b0r=0.f, b0i=0.f, b1r=0.f, b1i=0.f;
    for (int hb = 0; hb < 4; hb++){
      int m = ((hb*16)*fp) & 63;
      float twr = ct64[m], twi = -st64[m];
      for (int hh2 = 0; hh2 < 16; hh2++){
        int h = hb*16 + hh2;
        float sg = (h & 1) ? -1.f : 1.f;
        #pragma unroll
        for (int j = 0; j < 4; j++){
          float Tr = t1r[h*34 + 4*g + j], Ti = t1i[h*34 + 4*g + j];
          float pr = Tr*twr - Ti*twi;
          float pi = Tr*twi + Ti*twr;
          a0r[j] += pr; a0i[j] += pi;
          a1r[j] += sg*pr; a1i[j] += sg*pi;
        }
        if (g == 0){
          float Tr = t1r[h*34 + 32], Ti = t1i[h*34 + 32];
          float pr = Tr*twr - Ti*twi, pi = Tr*twi + Ti*twr;
          b0r += pr; b0i += pi; b1r += sg*pr; b1i += sg*pi;
        }
        float nr = twr*stepr - twi*stepi, ni = twr*stepi + twi*stepr;
        twr = nr; twi = ni;
      }
    }
    size_t base = (size_t)plane*2112;
    #pragma unroll
    for (int j = 0; j < 4; j++){
      int k = 4*g + j;
      float r0 = a0r[j]*(1.f/64.f), i0 = a0i[j]*(1.f/64.f);
      float r1 = a1r[j]*(1.f/64.f), i1 = a1i[j]*(1.f/64.f);
      fre[base + fp*33 + k] = r0; fim[base + fp*33 + k] = i0;
      fab[base + fp*33 + k] = sqrtf(r0*r0 + i0*i0);
      fre[base + (fp+32)*33 + k] = r1; fim[base + (fp+32)*33 + k] = i1;
      fab[base + (fp+32)*33 + k] = sqrtf(r1*r1 + i1*i1);
    }
    if (g == 0){
      float r0 = b0r*(1.f/64.f), i0 = b0i*(1.f/64.f);
      float r1 = b1r*(1.f/64.f), i1 = b1i*(1.f/64.f);
      fre[base + fp*33 + 32] = r0; fim[base + fp*33 + 32] = i0;
      fab[base + fp*33 + 32] = sqrtf(r0*r0 + i0*i0);
      fre[base + (fp+32)*33 + 32] = r1; fim[base + (fp+32)*33 + 32] = i1;
      fab[base + (fp+32)*33 + 32] = sqrtf(r1*r1 + i1*i1);
    }
  }
}

// ------------------------------------------------ K3: m = gelu(W1 @ |xf| + b1)  (LDS weights)
__global__ __launch_bounds__(256) void k_cmix1(const float* __restrict__ fab,
    const float* __restrict__ w1, const float* __restrict__ b1, float* __restrict__ m){
  int bid = blockIdx.x;
  int pt = bid % 9; int og = (bid/9) % 24; int b = bid/216;
  int tid = threadIdx.x;
  int p = pt*256 + tid; bool act = p < 2112;
  __shared__ float wl[192*8];
  for (int idx = tid; idx < 1536; idx += 256){ int o = idx & 7, c = idx >> 3;
    wl[c*8 + o] = w1[(size_t)(og*8 + o)*192 + c]; }
  __syncthreads();
  float acc[8];
  #pragma unroll
  for (int o = 0; o < 8; o++) acc[o] = b1[og*8 + o];
  const float* xb = fab + (size_t)b*CI*2112 + p;
  for (int c = 0; c < 192; c++){
    float xv = act ? xb[(size_t)c*2112] : 0.f;
    float4 wa = *(const float4*)&wl[c*8];
    float4 wb4 = *(const float4*)&wl[c*8 + 4];
    acc[0] += xv*wa.x;  acc[1] += xv*wa.y;  acc[2] += xv*wa.z;  acc[3] += xv*wa.w;
    acc[4] += xv*wb4.x; acc[5] += xv*wb4.y; acc[6] += xv*wb4.z; acc[7] += xv*wb4.w;
  }
  if (act){
    #pragma unroll
    for (int o = 0; o < 8; o++){
      float a = acc[o];
      m[((size_t)b*192 + og*8 + o)*2112 + p] = 0.5f*a*(1.0f + erff(a*0.70710678118654752f));
    }
  }
}

// ------------------------------------------------ K4: mag = W2 @ m + b2; in-place (LDS weights)
__global__ __launch_bounds__(256) void k_cmix2(const float* __restrict__ m,
    const float* __restrict__ w2, const float* __restrict__ bi2,
    float* __restrict__ fre, float* __restrict__ fim, const float* __restrict__ fab){
  int bid = blockIdx.x;
  int pt = bid % 9; int og = (bid/9) % 24; int b = bid/216;
  int tid = threadIdx.x;
  int p = pt*256 + tid; bool act = p < 2112;
  __shared__ float wl[192*8];
  for (int idx = tid; idx < 1536; idx += 256){ int o = idx & 7, c = idx >> 3;
    wl[c*8 + o] = w2[(size_t)(og*8 + o)*192 + c]; }
  __syncthreads();
  float acc[8];
  #pragma unroll
  for (int o = 0; o < 8; o++) acc[o] = bi2[og*8 + o];
  const float* xb = m + (size_t)b*CI*2112 + p;
  for (int c = 0; c < 192; c++){
    float xv = act ? xb[(size_t)c*2112] : 0.f;
    float4 wa = *(const float4*)&wl[c*8];
    float4 wb4 = *(const float4*)&wl[c*8 + 4];
    acc[0] += xv*wa.x;  acc[1] += xv*wa.y;  acc[2] += xv*wa.z;  acc[3] += xv*wa.w;
    acc[4] += xv*wb4.x; acc[5] += xv*wb4.y; acc[6] += xv*wb4.z; acc[7] += xv*wb4.w;
  }
  if (act){
    #pragma unroll
    for (int o = 0; o < 8; o++){
      size_t id = ((size_t)b*192 + og*8 + o)*2112 + p;
      float ab = fab[id];
      float re, im;
      if (ab > 1e-30f){ float sc = acc[o]/ab; re = sc*fre[id]; im = sc*fim[id]; }
      else { re = acc[o]; im = 0.f; }
      fre[id] = re; fim[id] = im;
    }
  }
}

// ------------------------------------------------ K5b: convert weights -> bf16 [q][oc][ic]
__global__ __launch_bounds__(256) void k_cvt_w(const float* __restrict__ ww,
    unsigned short* __restrict__ wqb2){
  int idx = blockIdx.x*256 + threadIdx.x;
  if (idx >= 331776) return;
  int ic = idx % 192; int rest = idx / 192;
  int oc = rest % 192; int q = rest / 192;
  wqb2[idx] = f2bf(ww[((size_t)oc*192 + ic)*9 + q]);
}

// ------------------------------------------------ K5c: transpose lhb -> bf16 [img][pix][ic]
__global__ __launch_bounds__(256) void k_prep_lhT(const float* __restrict__ lhb,
    unsigned short* __restrict__ lhT){
  int id = blockIdx.x*256 + threadIdx.x;          // 294912 total
  int pix = id & 1023;
  int icg = (id >> 10) % 24;
  int img = id / 24576;
  const float* s = lhb + (size_t)img*196608 + (size_t)(icg*8)*1024 + pix;
  v8us v;
  #pragma unroll
  for (int j = 0; j < 8; j++) v[j] = f2bf(s[(size_t)j*1024]);
  *(v8us*)&lhT[((size_t)img*1024 + pix)*192 + icg*8] = v;
}

// ------------------------------------------------ K6: 3x3 full conv via bf16 MFMA
__global__ __launch_bounds__(256) void k_wconv_mfma(const unsigned short* __restrict__ lhT,
    const unsigned short* __restrict__ wqb2, float* __restrict__ wnew){
  int bid = blockIdx.x;
  int nt = bid % 3; int mt = (bid/3) & 15; int img = bid/48;
  int o0 = nt*64;
  __shared__ __align__(16) unsigned short sm_us[26112];  // 52224 B: A band [136 pix][192 ic], swizzled
  unsigned short* Aband = sm_us;
  float* T = (float*)sm_us;                 // epilogue alias [64 m][65]
  int tid = threadIdx.x;
  int lane = tid & 63, wv = tid >> 6;
  int quad = lane >> 4, n16 = lane & 15;
  const unsigned short* wrow = wqb2 + ((size_t)(o0 + 16*wv + n16))*192 + quad*8;
  v8us bcur[6], bnxt[6];
  #pragma unroll
  for (int icc = 0; icc < 6; icc++) bcur[icc] = *(const v8us*)&wrow[icc*32];
  for (int i = tid; i < 3264; i += 256) ((v8us*)sm_us)[i] = (v8us){0,0,0,0,0,0,0,0};
  __syncthreads();
  const unsigned short* base = lhT + (size_t)img*196608;
  for (int idx = tid; idx < 3072; idx += 256){
    int r = idx / 768; int t = idx - r*768;
    int pc = t / 24;   int icg = t - pc*24;
    int gr = 2*mt - 1 + r;
    if (gr >= 0 && gr < 32){
      v8us v = *(const v8us*)&base[((size_t)gr*32 + pc)*192 + icg*8];
      int pix = r*34 + 1 + pc;
      *(v8us*)&Aband[pix*192 + ((icg*8) ^ ((pix & 7) << 3))] = v;
    }
  }
  __syncthreads();
  v4f acc[4];
  #pragma unroll
  for (int t2 = 0; t2 < 4; t2++) acc[t2] = (v4f){0.f,0.f,0.f,0.f};
  #pragma unroll
  for (int q = 0; q < 9; q++){
    int ky = q/3, kx = q - ky*3;
    if (q < 8){
      #pragma unroll
      for (int icc = 0; icc < 6; icc++)
        bnxt[icc] = *(const v8us*)&wrow[(size_t)(q+1)*36864 + icc*32];
    }
    #pragma unroll
    for (int icc = 0; icc < 6; icc++){
      int c0 = icc*32;
      v8bf bv = __builtin_bit_cast(v8bf, bcur[icc]);
      #pragma unroll
      for (int t2 = 0; t2 < 4; t2++){
        int mm = t2*16 + n16;
        int pix = ((mm >> 5) + ky)*34 + (mm & 31) + kx;
        const unsigned short* Ap = &Aband[pix*192 + ((c0 + quad*8) ^ ((pix & 7) << 3))];
        v8bf av = __builtin_bit_cast(v8bf, *(const v8us*)Ap);
        acc[t2] = __builtin_amdgcn_mfma_f32_16x16x32_bf16(av, bv, acc[t2], 0, 0, 0);
      }
    }
    #pragma unroll
    for (int icc = 0; icc < 6; icc++) bcur[icc] = bnxt[icc];
  }
  __syncthreads();
  #pragma unroll
  for (int t2 = 0; t2 < 4; t2++)
    #pragma unroll
    for (int r = 0; r < 4; r++)
      T[(16*t2 + quad*4 + r)*65 + 16*wv + n16] = acc[t2][r];
  __syncthreads();
  float* outb = wnew + (size_t)img*196608;
  for (int idx = tid; idx < 4096; idx += 256){
    int mm = idx & 63, oc = idx >> 6;
    outb[(size_t)(o0 + oc)*1024 + mt*64 + mm] = T[mm*65 + oc];
  }
}

// ------------------------------------------------ K7 (fused): irfft2 + combine + depthwise3x3 + SiLU -> ab, aT
__global__ __launch_bounds__(256) void k_ifwd(const float* __restrict__ fre2,
    const float* __restrict__ fim2, const float* __restrict__ xc,
    const float* __restrict__ ll, const float* __restrict__ wnew, const float* __restrict__ wb,
    const float* __restrict__ dww, const float* __restrict__ dwb,
    float* __restrict__ ab, float* __restrict__ aT){
  int plane = blockIdx.x;
  int c = plane % 192;
  __shared__ __align__(16) float sm[13504];   // 54016 B -> still 3 blocks/CU
  float* gr  = sm;             // [64][36]
  float* gi  = sm + 2304;
  float* ur  = sm + 4608;      // [64][36]
  float* ui  = sm + 6912;
  float* sx2 = sm + 9216;      // [64][65]
  float* t64r = sm + 13376; float* t64i = sm + 13440;
  float* scratch = sm;         // epilogue alias [64][65] (gr/gi dead by then)
  int tid = threadIdx.x;
  {
    size_t gbase = (size_t)plane*2112;
    for (int idx = tid; idx < 528; idx += 256){
      float4 vr_ = *(const float4*)&fre2[gbase + 4*idx];
      float4 vi_ = *(const float4*)&fim2[gbase + 4*idx];
      #pragma unroll
      for (int e = 0; e < 4; e++){
        int i = 4*idx + e;
        int f = i/33, k = i - f*33;
        float re = (e==0)?vr_.x:((e==1)?vr_.y:((e==2)?vr_.z:vr_.w));
        float im = (e==0)?vi_.x:((e==1)?vi_.y:((e==2)?vi_.z:vi_.w));
        gr[f*36 + k] = re; gi[f*36 + k] = im;
      }
    }
  }
  if (tid < 64){ t64r[tid] = cospif((float)tid/32.0f); t64i[tid] = sinpif((float)tid/32.0f); }
  __syncthreads();
  {
    int hp = tid & 31, g = tid >> 5;
    float stepr = cospif((float)hp/32.0f), stepi = sinpif((float)hp/32.0f);
    v4f a0r = (v4f)0.f, a0i = (v4f)0.f, a1r = (v4f)0.f, a1i = (v4f)0.f;
    float b0r=0.f, b0i=0.f, b1r=0.f, b1i=0.f;
    for (int fb = 0; fb < 4; fb++){
      int m = ((fb*16)*hp) & 63;
      float twr = t64r[m], twi = t64i[m];
      for (int ff = 0; ff < 16; ff++){
        int f = fb*16 + ff;
        float sg = (f & 1) ? -1.f : 1.f;
        v4f Gr = *(const v4f*)&gr[f*36 + 4*g];
        v4f Gi = *(const v4f*)&gi[f*36 + 4*g];
        v4f pr = Gr*twr - Gi*twi;
        v4f pi = Gr*twi + Gi*twr;
        a0r += pr; a0i += pi;
        a1r += sg*pr; a1i += sg*pi;
        if (g == 0){
          float Tr = gr[f*36 + 32], Ti = gi[f*36 + 32];
          float prs = Tr*twr - Ti*twi, pis = Tr*twi + Ti*twr;
          b0r += prs; b0i += pis; b1r += sg*prs; b1i += sg*pis;
        }
        float nr = twr*stepr - twi*stepi, ni = twr*stepi + twi*stepr;
        twr = nr; twi = ni;
      }
    }
    #pragma unroll
    for (int j = 0; j < 4; j++){
      int k = 4*g + j;
      float ck = (k == 0) ? (1.f/64.f) : (2.f/64.f);
      ur[hp*36 + k] = a0r[j]*ck;       ui[hp*36 + k] = a0i[j]*ck;
      ur[(hp+32)*36 + k] = a1r[j]*ck;  ui[(hp+32)*36 + k] = a1i[j]*ck;
    }
    if (g == 0){
      ur[hp*36 + 32] = b0r*(1.f/64.f);      ui[hp*36 + 32] = b0i*(1.f/64.f);
      ur[(hp+32)*36 + 32] = b1r*(1.f/64.f); ui[(hp+32)*36 + 32] = b1i*(1.f/64.f);
    }
  }
  __syncthreads();
  {
    int h = tid & 63, wg = tid >> 6;
    v8f accL = (v8f)0.f, accH = (v8f)0.f, twr, twi, sr, si;
    #pragma unroll
    for (int j = 0; j < 8; j++){
      int wl = 8*wg + j;
      sr[j] = t64r[wl]; si[j] = t64i[wl];
      twr[j] = 1.f; twi[j] = 0.f;
    }
    float acc32 = 0.f;
    for (int kb = 0; kb < 8; kb++){
      v4f U4 = *(const v4f*)&ur[h*36 + 4*kb];
      v4f V4 = *(const v4f*)&ui[h*36 + 4*kb];
      #pragma unroll
      for (int e = 0; e < 4; e++){
        int k = 4*kb + e;
        float Ur = U4[e], Ui = V4[e];
        if (wg == 0) acc32 += (k & 1) ? -Ur : Ur;
        v8f p = Ur*twr, q = Ui*twi;
        accL += p - q;
        accH += p + q;
        v8f nr = twr*sr - twi*si;
        v8f ni = twr*si + twi*sr;
        twr = nr; twi = ni;
      }
    }
    {
      float Ur = ur[h*36 + 32], Ui = ui[h*36 + 32];
      if (wg == 0) acc32 += Ur;
      v8f p = Ur*twr, q = Ui*twi;
      accL += p - q;
      accH += p + q;
    }
    #pragma unroll
    for (int j = 0; j < 8; j++){
      int wl = 8*wg + j;
      sx2[h*65 + wl] = accL[j];
      if (wl == 0) sx2[h*65 + 32] = acc32;
      else         sx2[h*65 + 64 - wl] = accH[j];
    }
  }
  __syncthreads();
  {
    float bia = wb[c];
    #pragma unroll
    for (int it = 0; it < 8; it++){
      int idx = tid + it*256;           // 2048 pairs
      int h = idx >> 5, pw = idx & 31;
      int w0 = pw*2;
      size_t q = (size_t)plane*1024 + (size_t)(h >> 1)*32 + pw;
      float LL = ll[q];
      float LH = wnew[q] + bia;
      float HL = wnew[786432 + q] + bia;
      float HH = wnew[1572864 + q] + bia;
      float2 xc2 = *(const float2*)&xc[(size_t)plane*4096 + h*64 + w0];
      float v0, v1;
      if (!(h & 1)){ v0 = (LL + LH + HL + HH)*0.5f; v1 = (LL - LH + HL - HH)*0.5f; }
      else         { v0 = (LL + LH - HL - HH)*0.5f; v1 = (LL - LH - HL + HH)*0.5f; }
      sx2[h*65 + w0]     += 2.0f*xc2.x + v0;
      sx2[h*65 + w0 + 1] += 2.0f*xc2.y + v1;
    }
  }
  __syncthreads();
  {
    float wk[9];
    #pragma unroll
    for (int q = 0; q < 9; q++) wk[q] = dww[c*9 + q];
    float dbv = dwb[c];
    int w = tid & 63, st = tid >> 6;
    int h0 = st*16;
    bool wl_ok = (w > 0), wr_ok = (w < 63);
    float r0l, r0c, r0r, r1l, r1c, r1r;
    if (h0 > 0){
      r0l = wl_ok ? sx2[(h0-1)*65 + w-1] : 0.f;
      r0c = sx2[(h0-1)*65 + w];
      r0r = wr_ok ? sx2[(h0-1)*65 + w+1] : 0.f;
    } else { r0l = 0.f; r0c = 0.f; r0r = 0.f; }
    r1l = wl_ok ? sx2[h0*65 + w-1] : 0.f;
    r1c = sx2[h0*65 + w];
    r1r = wr_ok ? sx2[h0*65 + w+1] : 0.f;
    #pragma unroll
    for (int hh2 = 0; hh2 < 16; hh2++){
      int h = h0 + hh2;
      float r2l, r2c, r2r;
      if (h < 63){
        r2l = wl_ok ? sx2[(h+1)*65 + w-1] : 0.f;
        r2c = sx2[(h+1)*65 + w];
        r2r = wr_ok ? sx2[(h+1)*65 + w+1] : 0.f;
      } else { r2l = 0.f; r2c = 0.f; r2r = 0.f; }
      float acc = dbv + r0l*wk[0] + r0c*wk[1] + r0r*wk[2]
                      + r1l*wk[3] + r1c*wk[4] + r1r*wk[5]
                      + r2l*wk[6] + r2c*wk[7] + r2r*wk[8];
      scratch[h*65 + w] = acc / (1.f + __expf(-acc));
      r0l = r1l; r0c = r1c; r0r = r1r;
      r1l = r2l; r1c = r2c; r1r = r2r;
    }
  }
  __syncthreads();
  float* abp = ab + (size_t)plane*4096;
  float* aTp = aT + (size_t)plane*4096;
  for (int p = tid; p < 4096; p += 256){
    abp[p] = scratch[(p >> 6)*65 + (p & 63)];
    aTp[p] = scratch[(p & 63)*65 + (p >> 6)];
  }
}

// ------------------------------------------------ K10: x_proj; wave-split GEMM
__global__ __launch_bounds__(256) void k_xproj(const float* __restrict__ ab,
    const float* __restrict__ aT, const float* __restrict__ xpw,
    float* __restrict__ Bsb, float* __restrict__ Csb, float* __restrict__ dlsb,
    float* __restrict__ xsb){
  int bid = blockIdx.x;
  int s = bid & 63; int k = (bid >> 6) & 3; int b = bid >> 8;
  int tid = threadIdx.x;
  __shared__ float als[96][65];
  __shared__ float dls[6][64];
  int l0 = s << 6;
  const float* src = (k & 1) ? aT : ab;
  bool rev = (k >= 2);
  int i = tid & 63, wg = tid >> 6;
  const float* wr[10];
  #pragma unroll
  for (int r = 0; r < 10; r++){
    int cp = wg + 4*r; if (cp > 37) cp = 37;
    int off = __builtin_amdgcn_readfirstlane((k*38 + cp)*192);
    wr[r] = xpw + off;
  }
  float acc[10];
  #pragma unroll
  for (int r = 0; r < 10; r++) acc[r] = 0.f;
  size_t xbase = ((size_t)(b*4 + k)*4096 + l0)*192;
  #pragma unroll
  for (int half = 0; half < 2; half++){
    int d0 = half*96;
    for (int idx = tid; idx < 1536; idx += 256){
      int d = idx >> 4, i4 = idx & 15;
      const float* rowp = src + ((size_t)b*192 + d0 + d)*4096;
      if (!rev){
        float4 v = *(const float4*)&rowp[l0 + 4*i4];
        als[d][4*i4+0] = v.x; als[d][4*i4+1] = v.y;
        als[d][4*i4+2] = v.z; als[d][4*i4+3] = v.w;
      } else {
        float4 v = *(const float4*)&rowp[4092 - l0 - 4*i4];
        als[d][4*i4+0] = v.w; als[d][4*i4+1] = v.z;
        als[d][4*i4+2] = v.y; als[d][4*i4+3] = v.x;
      }
    }
    __syncthreads();
    for (int d = 0; d < 96; d++){
      float v = als[d][i];
      #pragma unroll
      for (int r = 0; r < 10; r++) acc[r] += v*wr[r][d0 + d];
    }
    for (int idx = tid; idx < 1536; idx += 256){
      int ii = idx / 24, cc = (idx - (idx/24)*24)*4;
      float4 v;
      v.x = als[cc+0][ii]; v.y = als[cc+1][ii];
      v.z = als[cc+2][ii]; v.w = als[cc+3][ii];
      *(float4*)&xsb[xbase + (size_t)ii*192 + d0 + cc] = v;
    }
    __syncthreads();
  }
  #pragma unroll
  for (int r = 0; r < 10; r++){
    int cp = wg + 4*r;
    if (cp > 37) continue;
    if (cp < 6) dls[cp][i] = acc[r];
    else if (cp < 22) Bsb[((size_t)(b*4 + k)*16 + (cp - 6 ))*4096 + l0 + i] = acc[r];
    else              Csb[((size_t)(b*4 + k)*16 + (cp - 22))*4096 + l0 + i] = acc[r];
  }
  __syncthreads();
  size_t dbase = (size_t)((b*4 + k)*64 + s)*384;
  for (int j = tid; j < 384; j += 256){
    int ii = j/6, r = j - ii*6;
    dlsb[dbase + j] = dls[r][ii];
  }
}

// ------------------------------------------------ K11: scan phase A — v2: log-depth e1-power tree
__global__ __launch_bounds__(192) void k_scanA(const float* __restrict__ xsb,
    const float* __restrict__ dlsb, const float* __restrict__ Bsb,
    const float* __restrict__ dtw, const float* __restrict__ dtb,
    const float* __restrict__ alog, float* __restrict__ Pb, float* __restrict__ Qb){
  int bid = blockIdx.x; int s = bid & 63; int k = (bid >> 6) & 3; int b = bid >> 8;
  int c = threadIdx.x; int bk = b*4 + k;
  __shared__ float sdl[384];
  __shared__ float sB[16][64];
  size_t dbase = (size_t)(bk*64 + s)*384;
  for (int j = c; j < 384; j += 192) sdl[j] = dlsb[dbase + j];
  for (int j = c; j < 1024; j += 192){ int n = j >> 6, i = j & 63;
    sB[n][i] = Bsb[((size_t)bk*16 + n)*4096 + (s << 6) + i]; }
  __syncthreads();
  float A[16], P[16], Q[16];
  const float* arow = alog + ((size_t)k*192 + c)*16;
  bool fast = true;
  #pragma unroll
  for (int n = 0; n < 16; n++){
    A[n] = -__expf(arow[n]); P[n] = 1.f; Q[n] = 0.f;
    if (fabsf(A[n] + (float)(n+1)) > 1e-3f) fast = false;
  }
  float dw[6];
  #pragma unroll
  for (int r = 0; r < 6; r++) dw[r] = dtw[((size_t)k*192 + c)*6 + r];
  float db = dtb[k*192 + c];
  const float* xrow = xsb + ((size_t)bk*4096 + (s << 6))*192 + c;
  if (fast){
    for (int i = 0; i < 64; i++){
      float u = xrow[(size_t)i*192];
      float acc = db;
      #pragma unroll
      for (int r = 0; r < 6; r++) acc += sdl[i*6 + r]*dw[r];
      float ec = __expf(fminf(acc, 80.f));
      float e1 = __builtin_amdgcn_rcpf(1.f + ec);
      float du = __logf(1.f + ec)*u;
      float p2 = e1*e1, p4 = p2*p2, p8 = p4*p4;
      float E[16];
      E[0]=e1;      E[1]=p2;      E[2]=p2*e1;   E[3]=p4;
      E[4]=p4*e1;   E[5]=p4*p2;   E[6]=E[5]*e1; E[7]=p8;
      E[8]=p8*e1;   E[9]=p8*p2;   E[10]=E[9]*e1; E[11]=p8*p4;
      E[12]=E[11]*e1; E[13]=E[11]*p2; E[14]=E[13]*e1; E[15]=p8*p8;
      #pragma unroll
      for (int n = 0; n < 16; n++){
        P[n] *= E[n];
        Q[n] = Q[n]*E[n] + du*sB[n][i];
      }
    }
  } else {
    for (int i = 0; i < 64; i++){
      float u = xrow[(size_t)i*192];
      float acc = db;
      #pragma unroll
      for (int r = 0; r < 6; r++) acc += sdl[i*6 + r]*dw[r];
      float ec = __expf(fminf(acc, 80.f));
      float dl = __logf(1.f + ec);
      float du = dl*u;
      #pragma unroll
      for (int n = 0; n < 16; n++){
        float e = __expf(dl*A[n]);
        P[n] *= e;
        Q[n] = Q[n]*e + du*sB[n][i];
      }
    }
  }
  size_t pbase = ((size_t)(bk*64 + s)*16)*192 + c;
  #pragma unroll
  for (int n = 0; n < 16; n++){ Pb[pbase + (size_t)n*192] = P[n]; Qb[pbase + (size_t)n*192] = Q[n]; }
}

// ------------------------------------------------ K12: scan phase B (hin in-place over Pb)
__global__ __launch_bounds__(256) void k_scanB(float* __restrict__ Pb,
    const float* __restrict__ Qb){
  int id = blockIdx.x*256 + threadIdx.x;
  int c = id % 192; int rest = id / 192; int n = rest % 16; int bk = rest / 16;
  float h = 0.f;
  for (int s = 0; s < 64; s++){
    size_t o = (((size_t)bk*64 + s)*16 + n)*192 + c;
    float P = Pb[o], Q = Qb[o];
    Pb[o] = h;
    h = P*h + Q;
  }
}

// ------------------------------------------------ K13a: scan phase C — v2: log-depth e1-power
// tree + 4-partial y reduction.
__global__ __launch_bounds__(192) void k_scanC_buf(const float* __restrict__ xsb,
    const float* __restrict__ dlsb, const float* __restrict__ Bsb, const float* __restrict__ Csb,
    const float* __restrict__ hinb, const float* __restrict__ dtw, const float* __restrict__ dtb,
    const float* __restrict__ alog, const float* __restrict__ Dsp, float* __restrict__ Y){
  int bid = blockIdx.x; int s = bid & 63; int k = (bid >> 6) & 3; int b = bid >> 8;
  int c = threadIdx.x; int bk = b*4 + k;
  __shared__ float sdl[384];
  __shared__ float sB[16][64];
  __shared__ float sC[16][64];
  size_t dbase = (size_t)(bk*64 + s)*384;
  for (int j = c; j < 384; j += 192) sdl[j] = dlsb[dbase + j];
  for (int j = c; j < 1024; j += 192){ int n = j >> 6, i = j & 63;
    size_t o = ((size_t)bk*16 + n)*4096 + (s << 6) + i;
    sB[n][i] = Bsb[o]; sC[n][i] = Csb[o]; }
  __syncthreads();
  float A[16], h[16];
  const float* arow = alog + ((size_t)k*192 + c)*16;
  bool fast = true;
  #pragma unroll
  for (int n = 0; n < 16; n++){
    A[n] = -__expf(arow[n]);
    if (fabsf(A[n] + (float)(n+1)) > 1e-3f) fast = false;
  }
  size_t hbase = ((size_t)(bk*64 + s)*16)*192 + c;
  #pragma unroll
  for (int n = 0; n < 16; n++) h[n] = hinb[hbase + (size_t)n*192];
  float dw[6];
  #pragma unroll
  for (int r = 0; r < 6; r++) dw[r] = dtw[((size_t)k*192 + c)*6 + r];
  float db = dtb[k*192 + c];
  float Dc = Dsp[k*192 + c];
  const float* xrow = xsb + ((size_t)bk*4096 + (s << 6))*192 + c;
  float* Yk = Y + (((size_t)bk*4096 + (s << 6))*192) + c;
  if (fast){
    for (int i = 0; i < 64; i++){
      float u = xrow[(size_t)i*192];
      float acc = db;
      #pragma unroll
      for (int r = 0; r < 6; r++) acc += sdl[i*6 + r]*dw[r];
      float ec = __expf(fminf(acc, 80.f));
      float e1 = __builtin_amdgcn_rcpf(1.f + ec);
      float du = __logf(1.f + ec)*u;
      float p2 = e1*e1, p4 = p2*p2, p8 = p4*p4;
      float E[16];
      E[0]=e1;      E[1]=p2;      E[2]=p2*e1;   E[3]=p4;
      E[4]=p4*e1;   E[5]=p4*p2;   E[6]=E[5]*e1; E[7]=p8;
      E[8]=p8*e1;   E[9]=p8*p2;   E[10]=E[9]*e1; E[11]=p8*p4;
      E[12]=E[11]*e1; E[13]=E[11]*p2; E[14]=E[13]*e1; E[15]=p8*p8;
      float y0 = 0.f, y1 = 0.f, y2 = 0.f, y3 = 0.f;
      #pragma unroll
      for (int n = 0; n < 16; n++){
        h[n] = h[n]*E[n] + du*sB[n][i];
        float t = h[n]*sC[n][i];
        if ((n & 3) == 0) y0 += t;
        else if ((n & 3) == 1) y1 += t;
        else if ((n & 3) == 2) y2 += t;
        else y3 += t;
      }
      Yk[(size_t)i*192] = ((y0 + y1) + (y2 + y3)) + u*Dc;
    }
  } else {
    for (int i = 0; i < 64; i++){
      float u = xrow[(size_t)i*192];
      float acc = db;
      #pragma unroll
      for (int r = 0; r < 6; r++) acc += sdl[i*6 + r]*dw[r];
      float ec = __expf(fminf(acc, 80.f));
      float dl = __logf(1.f + ec);
      float du = dl*u;
      float y = 0.f;
      #pragma unroll
      for (int n = 0; n < 16; n++){
        float e = __expf(dl*A[n]);
        h[n] = h[n]*e + du*sB[n][i];
        y += h[n]*sC[n][i];
      }
      Yk[(size_t)i*192] = y + u*Dc;
    }
  }
}

// ------------------------------------------------ K13b: scan phase C — atomic fallback
__global__ __launch_bounds__(192) void k_scanC_atom(const float* __restrict__ xsb,
    const float* __restrict__ dlsb, const float* __restrict__ Bsb, const float* __restrict__ Csb,
    const float* __restrict__ hinb, const float* __restrict__ dtw, const float* __restrict__ dtb,
    const float* __restrict__ alog, const float* __restrict__ Dsp, float* __restrict__ yb){
  int bid = blockIdx.x; int s = bid & 63; int k = (bid >> 6) & 3; int b = bid >> 8;
  int c = threadIdx.x; int bk = b*4 + k;
  __shared__ float sdl[384];
  __shared__ float sB[16][64];
  __shared__ float sC[16][64];
  size_t dbase = (size_t)(bk*64 + s)*384;
  for (int j = c; j < 384; j += 192) sdl[j] = dlsb[dbase + j];
  for (int j = c; j < 1024; j += 192){ int n = j >> 6, i = j & 63;
    size_t o = ((size_t)bk*16 + n)*4096 + (s << 6) + i;
    sB[n][i] = Bsb[o]; sC[n][i] = Csb[o]; }
  __syncthreads();
  float A[16], h[16];
  const float* arow = alog + ((size_t)k*192 + c)*16;
  bool fast = true;
  #pragma unroll
  for (int n = 0; n < 16; n++){
    A[n] = -__expf(arow[n]);
    if (fabsf(A[n] + (float)(n+1)) > 1e-3f) fast = false;
  }
  size_t hbase = ((size_t)(bk*64 + s)*16)*192 + c;
  #pragma unroll
  for (int n = 0; n < 16; n++) h[n] = hinb[hbase + (size_t)n*192];
  float dw[6];
  #pragma unroll
  for (int r = 0; r < 6; r++) dw[r] = dtw[((size_t)k*192 + c)*6 + r];
  float db = dtb[k*192 + c];
  float Dc = Dsp[k*192 + c];
  const float* xrow = xsb + ((size_t)bk*4096 + (s << 6))*192 + c;
  int p0, pst;
  if (k == 0){ p0 = s << 6;        pst = 1;  }
  else if (k == 1){ p0 = s;        pst = 64; }
  else if (k == 2){ p0 = 4095 - (s << 6); pst = -1; }
  else { p0 = 4095 - s;            pst = -64; }
  for (int i = 0; i < 64; i++){
    float u = xrow[(size_t)i*192];
    float acc = db;
    #pragma unroll
    for (int r = 0; r < 6; r++) acc += sdl[i*6 + r]*dw[r];
    float ec = __expf(fminf(acc, 80.f));
    float dl = __logf(1.f + ec);
    float du = dl*u;
    float y = 0.f;
    if (fast){
      float e1 = __builtin_amdgcn_rcpf(1.f + ec);
      float e = 1.f;
      #pragma unroll
      for (int n = 0; n < 16; n++){
        e *= e1;
        h[n] = h[n]*e + du*sB[n][i];
        y += h[n]*sC[n][i];
      }
    } else {
      #pragma unroll
      for (int n = 0; n < 16; n++){
        float e = __expf(dl*A[n]);
        h[n] = h[n]*e + du*sB[n][i];
        y += h[n]*sC[n][i];
      }
    }
    y += u*Dc;
    atomicAdd(&yb[((size_t)b*4096 + p0 + pst*i)*192 + c], y);
  }
}

// ------------------------------------------------ K14b: symmetry enhance (atomic path)
__global__ __launch_bounds__(256) void k_enh(const float* __restrict__ yb,
    const float* __restrict__ symw, float* __restrict__ yfb){
  int id = blockIdx.x*256 + threadIdx.x;
  int c = id % 192; int rest = id / 192; int l = rest & 4095; int b = rest >> 12;
  int w = l & 63; int lr = (l | 63) - w;
  float v  = yb[id];
  float vr = yb[(((size_t)b << 12) + lr)*192 + c];
  float wg = 1.f/(1.f + __expf(-symw[0]));
  float enh = v*(1.f - wg) + 0.5f*(v + vr)*wg;
  yfb[id] = v + 0.2f*enh;
}

// ------------------------------------------------ K15a (fused, bigws): gather scan-order Y + enh + LN + out_proj
// v4 (restored from R9, measured 69 us): 32 mirror-pair rows, wt staged in TWO
// 96-c halves through an 18.4 KB buffer (LDS ~45 KB => 3 blocks/CU).
__global__ __launch_bounds__(256) void k_final_comb(const float* __restrict__ Y,
    const float* __restrict__ symw, const float* __restrict__ zT,
    const float* __restrict__ g, const float* __restrict__ bta,
    const float* __restrict__ opw, const float* __restrict__ x, float* __restrict__ out){
  int og = blockIdx.x & 1; int lt = (blockIdx.x >> 1) & 127; int b = blockIdx.x >> 8;
  int h = lt >> 1, wsel = lt & 1;
  __shared__ float sv[32][193];
  __shared__ float wtb[96*48];
  __shared__ float sg[192], sb2[192];
  __shared__ float smu[32], srs[32];
  __shared__ int lmap[32];
  int tid = threadIdx.x;
  const size_t S = (size_t)4096*192;
  float wg = 1.f/(1.f + __expf(-symw[0]));
  if (tid < 32){
    int r = tid;
    int w = (r < 16) ? (wsel*16 + r) : (63 - wsel*16 - (r - 16));
    lmap[r] = h*64 + w;
  }
  for (int idx = tid; idx < 1536; idx += 256){
    int r = idx / 48, c4 = (idx - (idx/48)*48)*4;
    int w = (r < 16) ? (wsel*16 + r) : (63 - wsel*16 - (r - 16));
    int l = h*64 + w;
    int p1 = (w << 6) | h;
    size_t base = (size_t)(b*4)*S + c4;
    float4 v0 = *(const float4*)&Y[base + (size_t)l*192];
    float4 v1 = *(const float4*)&Y[base + S + (size_t)p1*192];
    float4 v2 = *(const float4*)&Y[base + 2*S + (size_t)(4095 - l)*192];
    float4 v3 = *(const float4*)&Y[base + 3*S + (size_t)(4095 - p1)*192];
    sv[r][c4+0] = v0.x + v1.x + v2.x + v3.x;
    sv[r][c4+1] = v0.y + v1.y + v2.y + v3.y;
    sv[r][c4+2] = v0.z + v1.z + v2.z + v3.z;
    sv[r][c4+3] = v0.w + v1.w + v2.w + v3.w;
  }
  if (tid < 192){ sg[tid] = g[tid]; sb2[tid] = bta[tid]; }
  int o0 = og*48;
  // stage wt half-1: c in [0,96)
  for (int idx = tid; idx < 4608; idx += 256){ int o = idx % 48, c = idx/48;
    wtb[c*48 + o] = opw[(size_t)(o0 + o)*192 + c]; }
  __syncthreads();
  float yreg[24];
  #pragma unroll
  for (int t = 0; t < 24; t++){
    int idx = tid + t*256;
    int r = idx / 192, cc = idx - r*192;
    int rp = (r < 16) ? r + 16 : r - 16;
    float v = sv[r][cc], vp = sv[rp][cc];
    float enh = v*(1.f - wg) + 0.5f*(v + vp)*wg;
    yreg[t] = v + 0.2f*enh;
  }
  __syncthreads();
  #pragma unroll
  for (int t = 0; t < 24; t++){
    int idx = tid + t*256;
    int r = idx / 192, cc = idx - r*192;
    sv[r][cc] = yreg[t];
  }
  __syncthreads();
  if (tid < 32){
    float s1 = 0.f, s2 = 0.f;
    for (int c = 0; c < 192; c++){ float v = sv[tid][c]; s1 += v; s2 += v*v; }
    float mu = s1*(1.0f/192.0f);
    smu[tid] = mu; srs[tid] = rsqrtf(s2*(1.0f/192.0f) - mu*mu + 1e-5f);
  }
  __syncthreads();
  for (int idx = tid; idx < 6144; idx += 256){ int l = idx & 31, c = idx >> 5;
    float zv = zT[((size_t)b*192 + c)*4096 + lmap[l]];
    float v = sv[l][c];
    float yn = (v - smu[l])*srs[l]*sg[c] + sb2[c];
    sv[l][c] = yn * (zv/(1.f + __expf(-zv)));
  }
  __syncthreads();
  int l = tid & 31, grp = tid >> 5;
  float acc[6];
  #pragma unroll
  for (int j = 0; j < 6; j++) acc[j] = 0.f;
  // GEMM part 1: c in [0,96)
  for (int c = 0; c < 96; c++){
    float svv = sv[l][c];
    const float* wr = &wtb[c*48 + grp*6];
    #pragma unroll
    for (int j = 0; j < 6; j += 2){
      float2 w2 = *(const float2*)&wr[j];
      acc[j]   += svv*w2.x; acc[j+1] += svv*w2.y;
    }
  }
  __syncthreads();
  // stage wt half-2: c in [96,192)
  for (int idx = tid; idx < 4608; idx += 256){ int o = idx % 48, c = idx/48;
    wtb[c*48 + o] = opw[(size_t)(o0 + o)*192 + 96 + c]; }
  __syncthreads();
  for (int c = 0; c < 96; c++){
    float svv = sv[l][96 + c];
    const float* wr = &wtb[c*48 + grp*6];
    #pragma unroll
    for (int j = 0; j < 6; j += 2){
      float2 w2 = *(const float2*)&wr[j];
      acc[j]   += svv*w2.x; acc[j+1] += svv*w2.y;
    }
  }
  size_t ob = ((size_t)b*4096 + lmap[l])*96 + o0 + grp*6;
  #pragma unroll
  for (int j = 0; j < 6; j++) acc[j] += x[ob + j];
  #pragma unroll
  for (int j = 0; j < 6; j += 2){
    float2 v2; v2.x = acc[j]; v2.y = acc[j+1];
    *(float2*)&out[ob + j] = v2;
  }
}

// ------------------------------------------------ K15b: fallback
__global__ __launch_bounds__(256) void k_final(const float* __restrict__ yf,
    const float* __restrict__ zT, const float* __restrict__ g, const float* __restrict__ bta,
    const float* __restrict__ opw, const float* __restrict__ x, float* __restrict__ out){
  int og = blockIdx.x & 1; int lt = (blockIdx.x >> 1) & 127; int b = blockIdx.x >> 8;
  int l0 = lt << 5;
  __shared__ float sv[32][193];
  __shared__ float wt[192*48];
  __shared__ float sg[192], sb2[192];
  __shared__ float smu[32], srs[32];
  int tid = threadIdx.x;
  for (int idx = tid; idx < 6144; idx += 256){ int r = idx/192, c = idx - r*192;
    sv[r][c] = yf[((size_t)b*4096 + l0 + r)*192 + c]; }
  if (tid < 192){ sg[tid] = g[tid]; sb2[tid] = bta[tid]; }
  int o0 = og*48;
  for (int idx = tid; idx < 9216; idx += 256){ int o = idx % 48, c = idx/48;
    wt[c*48 + o] = opw[(size_t)(o0 + o)*192 + c]; }
  __syncthreads();
  if (tid < 32){
    float s1 = 0.f, s2 = 0.f;
    for (int c = 0; c < 192; c++){ float v = sv[tid][c]; s1 += v; s2 += v*v; }
    float mu = s1*(1.0f/192.0f);
    smu[tid] = mu; srs[tid] = rsqrtf(s2*(1.0f/192.0f) - mu*mu + 1e-5f);
  }
  __syncthreads();
  for (int idx = tid; idx < 6144; idx += 256){ int l = idx & 31, c = idx >> 5;
    float zv = zT[((size_t)b*192 + c)*4096 + l0 + l];
    float v = sv[l][c];
    float yn = (v - smu[l])*srs[l]*sg[c] + sb2[c];
    sv[l][c] = yn * (zv/(1.f + __expf(-zv)));
  }
  __syncthreads();
  int l = tid & 31, grp = tid >> 5;
  float acc[6];
  #pragma unroll
  for (int j = 0; j < 6; j++) acc[j] = 0.f;
  for (int c = 0; c < 192; c++){
    float svv = sv[l][c];
    const float* wr = &wt[c*48 + grp*6];
    #pragma unroll
    for (int j = 0; j < 6; j += 2){
      float2 w2 = *(const float2*)&wr[j];
      acc[j]   += svv*w2.x; acc[j+1] += svv*w2.y;
    }
  }
  size_t ob = ((size_t)b*4096 + l0 + l)*96 + o0 + grp*6;
  #pragma unroll
  for (int j = 0; j < 6; j++) acc[j] += x[ob + j];
  #pragma unroll
  for (int j = 0; j < 6; j += 2){
    float2 v2; v2.x = acc[j]; v2.y = acc[j+1];
    *(float2*)&out[ob + j] = v2;
  }
}

// ================================================================ host
extern "C" void kernel_launch(void* const* d_in, const int* in_sizes, int n_in,
                              void* d_out, int out_size, void* d_ws, size_t ws_size,
                              hipStream_t stream){
  (void)in_sizes; (void)n_in; (void)out_size;
  const float* ix   = (const float*)d_in[0];
  const float* ipw  = (const float*)d_in[1];
  const float* fw1  = (const float*)d_in[2];
  const float* fb1  = (const float*)d_in[3];
  const float* fw2  = (const float*)d_in[4];
  const float* fb2  = (const float*)d_in[5];
  const float* ww   = (const float*)d_in[6];
  const float* wb   = (const float*)d_in[7];
  const float* dww  = (const float*)d_in[8];
  const float* dwb  = (const float*)d_in[9];
  const float* symw = (const float*)d_in[10];
  const float* xpw  = (const float*)d_in[11];
  const float* dtw  = (const float*)d_in[12];
  const float* dtb  = (const float*)d_in[13];
  const float* alog = (const float*)d_in[14];
  const float* Dsp  = (const float*)d_in[15];
  const float* ong  = (const float*)d_in[16];
  const float* onb  = (const float*)d_in[17];
  const float* opw  = (const float*)d_in[18];
  const float* rmsw = (const float*)d_in[19];

  float* W = (float*)d_ws;
  const size_t SZ_BLC = 3145728, SZ_F = 1622016, SZ_H = 786432;
  float* zT  = W;
  float* ab  = zT + SZ_BLC;
  float* R0  = ab + SZ_BLC;
  // phase 1
  float* xc    = R0;
  float* fre   = xc  + SZ_BLC;
  float* fim   = fre + SZ_F;
  float* fab   = fim + SZ_F;
  float* mb    = fab + SZ_F;
  float* llb   = mb  + SZ_F;
  float* lhb   = llb + SZ_H;
  float* wnew  = lhb + 3*SZ_H;
  unsigned short* wqb2 = (unsigned short*)(wnew + 2359296);
  unsigned short* lhT  = wqb2 + 331776;   // 12 img x 1024 pix x 192 ic, bf16 (2.36M shorts)
  // phase 2
  float* Bsb  = R0;
  float* Csb  = Bsb + 1048576;
  float* dlsb = Csb + 1048576;
  float* xsb  = dlsb + 393216;
  float* Pb   = xsb + 12582912;
  float* aT   = Pb;
  float* Qb   = Pb + SZ_BLC;
  float* Yb   = Qb;                  // scan-order Y [bk][iscan][c]
  float* ybA  = Qb + SZ_BLC;
  float* yfb  = xsb;

  const size_t NEED_BIG = (size_t)(6291456 + 30801920) * 4;
  bool bigws = (ws_size >= NEED_BIG);

  hipLaunchKernelGGL(k_rms_inproj, dim3(2048),   dim3(256), 0, stream, ix, rmsw, ipw, xc, zT);
  hipLaunchKernelGGL(k_dft_fwd,    dim3(4*192),  dim3(256), 0, stream, xc, fre, fim, fab,
                     llb, lhb, lhb + SZ_H, lhb + 2*SZ_H);
  hipLaunchKernelGGL(k_cvt_w,      dim3(1296),   dim3(256), 0, stream, ww, wqb2);
  hipLaunchKernelGGL(k_prep_lhT,   dim3(1152),   dim3(256), 0, stream, lhb, lhT);
  hipLaunchKernelGGL(k_cmix1,      dim3(864),    dim3(256), 0, stream, fab, fw1, fb1, mb);
  hipLaunchKernelGGL(k_cmix2,      dim3(864),    dim3(256), 0, stream, mb, fw2, fb2, fre, fim, fab);
  hipLaunchKernelGGL(k_wconv_mfma, dim3(576),    dim3(256), 0, stream, lhT, wqb2, wnew);
  hipLaunchKernelGGL(k_ifwd,       dim3(768),    dim3(256), 0, stream, fre, fim, xc, llb, wnew, wb, dww, dwb, ab, aT);
  hipLaunchKernelGGL(k_xproj,      dim3(1024),   dim3(256), 0, stream, ab, aT, xpw, Bsb, Csb, dlsb, xsb);
  hipLaunchKernelGGL(k_scanA,      dim3(1024),   dim3(192), 0, stream, xsb, dlsb, Bsb, dtw, dtb, alog, Pb, Qb);
  hipLaunchKernelGGL(k_scanB,      dim3(192),    dim3(256), 0, stream, Pb, Qb);
  if (bigws){
    hipLaunchKernelGGL(k_scanC_buf,  dim3(1024), dim3(192), 0, stream, xsb, dlsb, Bsb, Csb, Pb, dtw, dtb, alog, Dsp, Yb);
    hipLaunchKernelGGL(k_final_comb, dim3(1024), dim3(256), 0, stream, Yb, symw, zT, ong, onb, opw, ix, (float*)d_out);
  } else {
    hipLaunchKernelGGL(k_zero,       dim3(12288), dim3(256), 0, stream, ybA, (int)SZ_BLC);
    hipLaunchKernelGGL(k_scanC_atom, dim3(1024),  dim3(192), 0, stream, xsb, dlsb, Bsb, Csb, Pb, dtw, dtb, alog, Dsp, ybA);
    hipLaunchKernelGGL(k_enh,        dim3(12288), dim3(256), 0, stream, ybA, symw, yfb);
    hipLaunchKernelGGL(k_final,      dim3(1024),  dim3(256), 0, stream, yfb, zT, ong, onb, opw, ix, (float*)d_out);
  }
}

// Round 12
// 532.581 us; speedup vs baseline: 1.9694x; 1.1120x over previous
//
#include <hip/hip_runtime.h>
#include <hip/hip_bf16.h>

#define CI 192
#define LL_ 4096

typedef __bf16 v8bf __attribute__((ext_vector_type(8)));
typedef float  v4f  __attribute__((ext_vector_type(4)));
typedef float  v8f  __attribute__((ext_vector_type(8)));
typedef unsigned short v8us __attribute__((ext_vector_type(8)));

__device__ __forceinline__ unsigned short f2bf(float v){
  unsigned int u = __float_as_uint(v);
  return (unsigned short)((u + 0x7FFFu + ((u >> 16) & 1u)) >> 16);
}

__global__ __launch_bounds__(256) void k_zero(float* __restrict__ p, int n){
  int i = blockIdx.x*256 + threadIdx.x;
  if (i < n) p[i] = 0.f;
}

// ------------------------------------------------ K1: RMSNorm + in_proj (tiled GEMM, 48-o tiles)
__global__ __launch_bounds__(256) void k_rms_inproj(const float* __restrict__ x,
    const float* __restrict__ rmsw, const float* __restrict__ ipw,
    float* __restrict__ xc, float* __restrict__ zT){
  int og = blockIdx.x & 7; int lt = (blockIdx.x >> 3) & 63; int b = blockIdx.x >> 9;
  int l0 = lt << 6;
  __shared__ float xt[64][97];
  __shared__ float wt[96*48];
  __shared__ float rr[64];
  __shared__ float rw[96];
  int tid = threadIdx.x;
  for (int idx = tid; idx < 6144; idx += 256){ int r = idx/96, d = idx - r*96;
    xt[r][d] = x[((size_t)b*4096 + l0 + r)*96 + d]; }
  if (tid < 96) rw[tid] = rmsw[tid];
  int o0 = og*48;
  for (int idx = tid; idx < 4608; idx += 256){ int o = idx%48, d = idx/48;
    wt[d*48 + o] = ipw[(size_t)(o0 + o)*96 + d]; }
  __syncthreads();
  if (tid < 64){
    float s = 0.f;
    for (int d = 0; d < 96; d++){ float v = xt[tid][d]; s += v*v; }
    rr[tid] = rsqrtf(s*(1.0f/96.0f) + 1e-5f);
  }
  __syncthreads();
  for (int idx = tid; idx < 6144; idx += 256){ int r = idx/96, d = idx - r*96;
    xt[r][d] *= rr[r]*rw[d]; }
  __syncthreads();
  int l = tid & 63, grp = tid >> 6;
  float acc[12];
  #pragma unroll
  for (int j = 0; j < 12; j++) acc[j] = 0.f;
  for (int d = 0; d < 96; d++){
    float xv = xt[l][d];
    const float* wr = &wt[d*48 + grp*12];
    #pragma unroll
    for (int j = 0; j < 12; j += 4){
      float4 w4 = *(const float4*)&wr[j];
      acc[j]   += xv*w4.x; acc[j+1] += xv*w4.y;
      acc[j+2] += xv*w4.z; acc[j+3] += xv*w4.w;
    }
  }
  #pragma unroll
  for (int j = 0; j < 12; j++){
    int o = o0 + grp*12 + j;
    if (o < 192) xc[((size_t)b*192 + o)*4096 + l0 + l] = acc[j];
    else         zT[((size_t)b*192 + (o-192))*4096 + l0 + l] = acc[j];
  }
}

// ------------------------------------------------ K2: forward rfft2 (ortho) + fused Haar DWT
__global__ __launch_bounds__(256) void k_dft_fwd(const float* __restrict__ xc,
    float* __restrict__ fre, float* __restrict__ fim, float* __restrict__ fab,
    float* __restrict__ ll, float* __restrict__ lh, float* __restrict__ hl, float* __restrict__ hh){
  int plane = blockIdx.x;
  __shared__ float sxT[64*65];
  __shared__ float t1r[64*34], t1i[64*34];
  __shared__ float tabr[16], tabi[16];
  __shared__ float ct64[64], st64[64];
  int tid = threadIdx.x;
  const float* X = xc + (size_t)plane*4096;
  for (int i = tid; i < 4096; i += 256){ int h = i >> 6, w = i & 63; sxT[w*65 + h] = X[i]; }
  if (tid < 16){ tabr[tid] = cospif((float)tid/8.0f); tabi[tid] = -sinpif((float)tid/8.0f); }
  if (tid < 64){ ct64[tid] = cospif((float)tid/32.0f); st64[tid] = sinpif((float)tid/32.0f); }
  __syncthreads();
  {
    size_t qbase = (size_t)plane*1024;
    for (int idx = tid; idx < 1024; idx += 256){
      int y2 = idx >> 5, x2 = idx & 31;
      float a_ = sxT[(2*x2)*65 + 2*y2],     b_ = sxT[(2*x2+1)*65 + 2*y2];
      float c_ = sxT[(2*x2)*65 + 2*y2+1],   d_ = sxT[(2*x2+1)*65 + 2*y2+1];
      ll[qbase + idx] = (a_+b_+c_+d_)*0.5f; lh[qbase + idx] = (a_-b_+c_-d_)*0.5f;
      hl[qbase + idx] = (a_+b_-c_-d_)*0.5f; hh[qbase + idx] = (a_-b_-c_+d_)*0.5f;
    }
  }
  {
    int hp = tid & 31, g = tid >> 5;
    float a0r[4], a0i[4], a1r[4], a1i[4];
    #pragma unroll
    for (int j = 0; j < 4; j++){ a0r[j]=0.f; a0i[j]=0.f; a1r[j]=0.f; a1i[j]=0.f; }
    float s32_0 = 0.f, s32_1 = 0.f;
    for (int w = 0; w < 64; w++){
      float xv0 = sxT[w*65 + hp];
      float xv1 = sxT[w*65 + hp + 32];
      int m0 = (w*g) & 15;
      float twr = tabr[m0], twi = tabi[m0];
      int ms = w & 15;
      float str = tabr[ms], sti = tabi[ms];
      #pragma unroll
      for (int j = 0; j < 4; j++){
        a0r[j] += xv0*twr; a0i[j] += xv0*twi;
        a1r[j] += xv1*twr; a1i[j] += xv1*twi;
        float nr = twr*str - twi*sti;
        float ni = twr*sti + twi*str;
        twr = nr; twi = ni;
      }
      if (g == 0){ float sg = (w & 1) ? -1.f : 1.f; s32_0 += xv0*sg; s32_1 += xv1*sg; }
    }
    #pragma unroll
    for (int j = 0; j < 4; j++){
      int k = 4*g + j;
      t1r[hp*34 + k] = a0r[j];        t1i[hp*34 + k] = a0i[j];
      t1r[(hp+32)*34 + k] = a1r[j];   t1i[(hp+32)*34 + k] = a1i[j];
    }
    if (g == 0){
      t1r[hp*34 + 32] = s32_0;      t1i[hp*34 + 32] = 0.f;
      t1r[(hp+32)*34 + 32] = s32_1; t1i[(hp+32)*34 + 32] = 0.f;
    }
  }
  __syncthreads();
  {
    int fp = tid & 31, g = tid >> 5;
    float stepr = cospif((float)fp/32.0f), stepi = -sinpif((float)fp/32.0f);
    float a0r[4], a0i[4], a1r[4], a1i[4];
    #pragma unroll
    for (int j = 0; j < 4; j++){ a0r[j]=0.f; a0i[j]=0.f; a1r[j]=0.f; a1i[j]=0.f; }
    float b0r=0.f, b0i=0.f, b1r=0.f, b1i=0.f;
    for (int hb = 0; hb < 4; hb++){
      int m = ((hb*16)*fp) & 63;
      float twr = ct64[m], twi = -st64[m];
      for (int hh2 = 0; hh2 < 16; hh2++){
        int h = hb*16 + hh2;
        float sg = (h & 1) ? -1.f : 1.f;
        #pragma unroll
        for (int j = 0; j < 4; j++){
          float Tr = t1r[h*34 + 4*g + j], Ti = t1i[h*34 + 4*g + j];
          float pr = Tr*twr - Ti*twi;
          float pi = Tr*twi + Ti*twr;
          a0r[j] += pr; a0i[j] += pi;
          a1r[j] += sg*pr; a1i[j] += sg*pi;
        }
        if (g == 0){
          float Tr = t1r[h*34 + 32], Ti = t1i[h*34 + 32];
          float pr = Tr*twr - Ti*twi, pi = Tr*twi + Ti*twr;
          b0r += pr; b0i += pi; b1r += sg*pr; b1i += sg*pi;
        }
        float nr = twr*stepr - twi*stepi, ni = twr*stepi + twi*stepr;
        twr = nr; twi = ni;
      }
    }
    size_t base = (size_t)plane*2112;
    #pragma unroll
    for (int j = 0; j < 4; j++){
      int k = 4*g + j;
      float r0 = a0r[j]*(1.f/64.f), i0 = a0i[j]*(1.f/64.f);
      float r1 = a1r[j]*(1.f/64.f), i1 = a1i[j]*(1.f/64.f);
      fre[base + fp*33 + k] = r0; fim[base + fp*33 + k] = i0;
      fab[base + fp*33 + k] = sqrtf(r0*r0 + i0*i0);
      fre[base + (fp+32)*33 + k] = r1; fim[base + (fp+32)*33 + k] = i1;
      fab[base + (fp+32)*33 + k] = sqrtf(r1*r1 + i1*i1);
    }
    if (g == 0){
      float r0 = b0r*(1.f/64.f), i0 = b0i*(1.f/64.f);
      float r1 = b1r*(1.f/64.f), i1 = b1i*(1.f/64.f);
      fre[base + fp*33 + 32] = r0; fim[base + fp*33 + 32] = i0;
      fab[base + fp*33 + 32] = sqrtf(r0*r0 + i0*i0);
      fre[base + (fp+32)*33 + 32] = r1; fim[base + (fp+32)*33 + 32] = i1;
      fab[base + (fp+32)*33 + 32] = sqrtf(r1*r1 + i1*i1);
    }
  }
}

// ------------------------------------------------ K3: m = gelu(W1 @ |xf| + b1)  (LDS weights)
__global__ __launch_bounds__(256) void k_cmix1(const float* __restrict__ fab,
    const float* __restrict__ w1, const float* __restrict__ b1, float* __restrict__ m){
  int bid = blockIdx.x;
  int pt = bid % 9; int og = (bid/9) % 24; int b = bid/216;
  int tid = threadIdx.x;
  int p = pt*256 + tid; bool act = p < 2112;
  __shared__ float wl[192*8];
  for (int idx = tid; idx < 1536; idx += 256){ int o = idx & 7, c = idx >> 3;
    wl[c*8 + o] = w1[(size_t)(og*8 + o)*192 + c]; }
  __syncthreads();
  float acc[8];
  #pragma unroll
  for (int o = 0; o < 8; o++) acc[o] = b1[og*8 + o];
  const float* xb = fab + (size_t)b*CI*2112 + p;
  for (int c = 0; c < 192; c++){
    float xv = act ? xb[(size_t)c*2112] : 0.f;
    float4 wa = *(const float4*)&wl[c*8];
    float4 wb4 = *(const float4*)&wl[c*8 + 4];
    acc[0] += xv*wa.x;  acc[1] += xv*wa.y;  acc[2] += xv*wa.z;  acc[3] += xv*wa.w;
    acc[4] += xv*wb4.x; acc[5] += xv*wb4.y; acc[6] += xv*wb4.z; acc[7] += xv*wb4.w;
  }
  if (act){
    #pragma unroll
    for (int o = 0; o < 8; o++){
      float a = acc[o];
      m[((size_t)b*192 + og*8 + o)*2112 + p] = 0.5f*a*(1.0f + erff(a*0.70710678118654752f));
    }
  }
}

// ------------------------------------------------ K4: mag = W2 @ m + b2; in-place (LDS weights)
__global__ __launch_bounds__(256) void k_cmix2(const float* __restrict__ m,
    const float* __restrict__ w2, const float* __restrict__ bi2,
    float* __restrict__ fre, float* __restrict__ fim, const float* __restrict__ fab){
  int bid = blockIdx.x;
  int pt = bid % 9; int og = (bid/9) % 24; int b = bid/216;
  int tid = threadIdx.x;
  int p = pt*256 + tid; bool act = p < 2112;
  __shared__ float wl[192*8];
  for (int idx = tid; idx < 1536; idx += 256){ int o = idx & 7, c = idx >> 3;
    wl[c*8 + o] = w2[(size_t)(og*8 + o)*192 + c]; }
  __syncthreads();
  float acc[8];
  #pragma unroll
  for (int o = 0; o < 8; o++) acc[o] = bi2[og*8 + o];
  const float* xb = m + (size_t)b*CI*2112 + p;
  for (int c = 0; c < 192; c++){
    float xv = act ? xb[(size_t)c*2112] : 0.f;
    float4 wa = *(const float4*)&wl[c*8];
    float4 wb4 = *(const float4*)&wl[c*8 + 4];
    acc[0] += xv*wa.x;  acc[1] += xv*wa.y;  acc[2] += xv*wa.z;  acc[3] += xv*wa.w;
    acc[4] += xv*wb4.x; acc[5] += xv*wb4.y; acc[6] += xv*wb4.z; acc[7] += xv*wb4.w;
  }
  if (act){
    #pragma unroll
    for (int o = 0; o < 8; o++){
      size_t id = ((size_t)b*192 + og*8 + o)*2112 + p;
      float ab = fab[id];
      float re, im;
      if (ab > 1e-30f){ float sc = acc[o]/ab; re = sc*fre[id]; im = sc*fim[id]; }
      else { re = acc[o]; im = 0.f; }
      fre[id] = re; fim[id] = im;
    }
  }
}

// ------------------------------------------------ K5b: convert weights -> bf16 [q][oc][ic]
__global__ __launch_bounds__(256) void k_cvt_w(const float* __restrict__ ww,
    unsigned short* __restrict__ wqb2){
  int idx = blockIdx.x*256 + threadIdx.x;
  if (idx >= 331776) return;
  int ic = idx % 192; int rest = idx / 192;
  int oc = rest % 192; int q = rest / 192;
  wqb2[idx] = f2bf(ww[((size_t)oc*192 + ic)*9 + q]);
}

// ------------------------------------------------ K5c: transpose lhb -> bf16 [img][pix][ic]
__global__ __launch_bounds__(256) void k_prep_lhT(const float* __restrict__ lhb,
    unsigned short* __restrict__ lhT){
  int id = blockIdx.x*256 + threadIdx.x;          // 294912 total
  int pix = id & 1023;
  int icg = (id >> 10) % 24;
  int img = id / 24576;
  const float* s = lhb + (size_t)img*196608 + (size_t)(icg*8)*1024 + pix;
  v8us v;
  #pragma unroll
  for (int j = 0; j < 8; j++) v[j] = f2bf(s[(size_t)j*1024]);
  *(v8us*)&lhT[((size_t)img*1024 + pix)*192 + icg*8] = v;
}

// ------------------------------------------------ K6: 3x3 full conv via bf16 MFMA
__global__ __launch_bounds__(256) void k_wconv_mfma(const unsigned short* __restrict__ lhT,
    const unsigned short* __restrict__ wqb2, float* __restrict__ wnew){
  int bid = blockIdx.x;
  int nt = bid % 3; int mt = (bid/3) & 15; int img = bid/48;
  int o0 = nt*64;
  __shared__ __align__(16) unsigned short sm_us[26112];  // 52224 B: A band [136 pix][192 ic], swizzled
  unsigned short* Aband = sm_us;
  float* T = (float*)sm_us;                 // epilogue alias [64 m][65]
  int tid = threadIdx.x;
  int lane = tid & 63, wv = tid >> 6;
  int quad = lane >> 4, n16 = lane & 15;
  const unsigned short* wrow = wqb2 + ((size_t)(o0 + 16*wv + n16))*192 + quad*8;
  v8us bcur[6], bnxt[6];
  #pragma unroll
  for (int icc = 0; icc < 6; icc++) bcur[icc] = *(const v8us*)&wrow[icc*32];
  for (int i = tid; i < 3264; i += 256) ((v8us*)sm_us)[i] = (v8us){0,0,0,0,0,0,0,0};
  __syncthreads();
  const unsigned short* base = lhT + (size_t)img*196608;
  for (int idx = tid; idx < 3072; idx += 256){
    int r = idx / 768; int t = idx - r*768;
    int pc = t / 24;   int icg = t - pc*24;
    int gr = 2*mt - 1 + r;
    if (gr >= 0 && gr < 32){
      v8us v = *(const v8us*)&base[((size_t)gr*32 + pc)*192 + icg*8];
      int pix = r*34 + 1 + pc;
      *(v8us*)&Aband[pix*192 + ((icg*8) ^ ((pix & 7) << 3))] = v;
    }
  }
  __syncthreads();
  v4f acc[4];
  #pragma unroll
  for (int t2 = 0; t2 < 4; t2++) acc[t2] = (v4f){0.f,0.f,0.f,0.f};
  #pragma unroll
  for (int q = 0; q < 9; q++){
    int ky = q/3, kx = q - ky*3;
    if (q < 8){
      #pragma unroll
      for (int icc = 0; icc < 6; icc++)
        bnxt[icc] = *(const v8us*)&wrow[(size_t)(q+1)*36864 + icc*32];
    }
    #pragma unroll
    for (int icc = 0; icc < 6; icc++){
      int c0 = icc*32;
      v8bf bv = __builtin_bit_cast(v8bf, bcur[icc]);
      #pragma unroll
      for (int t2 = 0; t2 < 4; t2++){
        int mm = t2*16 + n16;
        int pix = ((mm >> 5) + ky)*34 + (mm & 31) + kx;
        const unsigned short* Ap = &Aband[pix*192 + ((c0 + quad*8) ^ ((pix & 7) << 3))];
        v8bf av = __builtin_bit_cast(v8bf, *(const v8us*)Ap);
        acc[t2] = __builtin_amdgcn_mfma_f32_16x16x32_bf16(av, bv, acc[t2], 0, 0, 0);
      }
    }
    #pragma unroll
    for (int icc = 0; icc < 6; icc++) bcur[icc] = bnxt[icc];
  }
  __syncthreads();
  #pragma unroll
  for (int t2 = 0; t2 < 4; t2++)
    #pragma unroll
    for (int r = 0; r < 4; r++)
      T[(16*t2 + quad*4 + r)*65 + 16*wv + n16] = acc[t2][r];
  __syncthreads();
  float* outb = wnew + (size_t)img*196608;
  for (int idx = tid; idx < 4096; idx += 256){
    int mm = idx & 63, oc = idx >> 6;
    outb[(size_t)(o0 + oc)*1024 + mt*64 + mm] = T[mm*65 + oc];
  }
}

// ------------------------------------------------ K7 (fused): irfft2 + combine + depthwise3x3 + SiLU -> ab, aT
__global__ __launch_bounds__(256) void k_ifwd(const float* __restrict__ fre2,
    const float* __restrict__ fim2, const float* __restrict__ xc,
    const float* __restrict__ ll, const float* __restrict__ wnew, const float* __restrict__ wb,
    const float* __restrict__ dww, const float* __restrict__ dwb,
    float* __restrict__ ab, float* __restrict__ aT){
  int plane = blockIdx.x;
  int c = plane % 192;
  __shared__ __align__(16) float sm[13504];   // 54016 B -> still 3 blocks/CU
  float* gr  = sm;             // [64][36]
  float* gi  = sm + 2304;
  float* ur  = sm + 4608;      // [64][36]
  float* ui  = sm + 6912;
  float* sx2 = sm + 9216;      // [64][65]
  float* t64r = sm + 13376; float* t64i = sm + 13440;
  float* scratch = sm;         // epilogue alias [64][65] (gr/gi dead by then)
  int tid = threadIdx.x;
  {
    size_t gbase = (size_t)plane*2112;
    for (int idx = tid; idx < 528; idx += 256){
      float4 vr_ = *(const float4*)&fre2[gbase + 4*idx];
      float4 vi_ = *(const float4*)&fim2[gbase + 4*idx];
      #pragma unroll
      for (int e = 0; e < 4; e++){
        int i = 4*idx + e;
        int f = i/33, k = i - f*33;
        float re = (e==0)?vr_.x:((e==1)?vr_.y:((e==2)?vr_.z:vr_.w));
        float im = (e==0)?vi_.x:((e==1)?vi_.y:((e==2)?vi_.z:vi_.w));
        gr[f*36 + k] = re; gi[f*36 + k] = im;
      }
    }
  }
  if (tid < 64){ t64r[tid] = cospif((float)tid/32.0f); t64i[tid] = sinpif((float)tid/32.0f); }
  __syncthreads();
  {
    int hp = tid & 31, g = tid >> 5;
    float stepr = cospif((float)hp/32.0f), stepi = sinpif((float)hp/32.0f);
    v4f a0r = (v4f)0.f, a0i = (v4f)0.f, a1r = (v4f)0.f, a1i = (v4f)0.f;
    float b0r=0.f, b0i=0.f, b1r=0.f, b1i=0.f;
    for (int fb = 0; fb < 4; fb++){
      int m = ((fb*16)*hp) & 63;
      float twr = t64r[m], twi = t64i[m];
      for (int ff = 0; ff < 16; ff++){
        int f = fb*16 + ff;
        float sg = (f & 1) ? -1.f : 1.f;
        v4f Gr = *(const v4f*)&gr[f*36 + 4*g];
        v4f Gi = *(const v4f*)&gi[f*36 + 4*g];
        v4f pr = Gr*twr - Gi*twi;
        v4f pi = Gr*twi + Gi*twr;
        a0r += pr; a0i += pi;
        a1r += sg*pr; a1i += sg*pi;
        if (g == 0){
          float Tr = gr[f*36 + 32], Ti = gi[f*36 + 32];
          float prs = Tr*twr - Ti*twi, pis = Tr*twi + Ti*twr;
          b0r += prs; b0i += pis; b1r += sg*prs; b1i += sg*pis;
        }
        float nr = twr*stepr - twi*stepi, ni = twr*stepi + twi*stepr;
        twr = nr; twi = ni;
      }
    }
    #pragma unroll
    for (int j = 0; j < 4; j++){
      int k = 4*g + j;
      float ck = (k == 0) ? (1.f/64.f) : (2.f/64.f);
      ur[hp*36 + k] = a0r[j]*ck;       ui[hp*36 + k] = a0i[j]*ck;
      ur[(hp+32)*36 + k] = a1r[j]*ck;  ui[(hp+32)*36 + k] = a1i[j]*ck;
    }
    if (g == 0){
      ur[hp*36 + 32] = b0r*(1.f/64.f);      ui[hp*36 + 32] = b0i*(1.f/64.f);
      ur[(hp+32)*36 + 32] = b1r*(1.f/64.f); ui[(hp+32)*36 + 32] = b1i*(1.f/64.f);
    }
  }
  __syncthreads();
  {
    int h = tid & 63, wg = tid >> 6;
    v8f accL = (v8f)0.f, accH = (v8f)0.f, twr, twi, sr, si;
    #pragma unroll
    for (int j = 0; j < 8; j++){
      int wl = 8*wg + j;
      sr[j] = t64r[wl]; si[j] = t64i[wl];
      twr[j] = 1.f; twi[j] = 0.f;
    }
    float acc32 = 0.f;
    for (int kb = 0; kb < 8; kb++){
      v4f U4 = *(const v4f*)&ur[h*36 + 4*kb];
      v4f V4 = *(const v4f*)&ui[h*36 + 4*kb];
      #pragma unroll
      for (int e = 0; e < 4; e++){
        int k = 4*kb + e;
        float Ur = U4[e], Ui = V4[e];
        if (wg == 0) acc32 += (k & 1) ? -Ur : Ur;
        v8f p = Ur*twr, q = Ui*twi;
        accL += p - q;
        accH += p + q;
        v8f nr = twr*sr - twi*si;
        v8f ni = twr*si + twi*sr;
        twr = nr; twi = ni;
      }
    }
    {
      float Ur = ur[h*36 + 32], Ui = ui[h*36 + 32];
      if (wg == 0) acc32 += Ur;
      v8f p = Ur*twr, q = Ui*twi;
      accL += p - q;
      accH += p + q;
    }
    #pragma unroll
    for (int j = 0; j < 8; j++){
      int wl = 8*wg + j;
      sx2[h*65 + wl] = accL[j];
      if (wl == 0) sx2[h*65 + 32] = acc32;
      else         sx2[h*65 + 64 - wl] = accH[j];
    }
  }
  __syncthreads();
  {
    float bia = wb[c];
    #pragma unroll
    for (int it = 0; it < 8; it++){
      int idx = tid + it*256;           // 2048 pairs
      int h = idx >> 5, pw = idx & 31;
      int w0 = pw*2;
      size_t q = (size_t)plane*1024 + (size_t)(h >> 1)*32 + pw;
      float LL = ll[q];
      float LH = wnew[q] + bia;
      float HL = wnew[786432 + q] + bia;
      float HH = wnew[1572864 + q] + bia;
      float2 xc2 = *(const float2*)&xc[(size_t)plane*4096 + h*64 + w0];
      float v0, v1;
      if (!(h & 1)){ v0 = (LL + LH + HL + HH)*0.5f; v1 = (LL - LH + HL - HH)*0.5f; }
      else         { v0 = (LL + LH - HL - HH)*0.5f; v1 = (LL - LH - HL + HH)*0.5f; }
      sx2[h*65 + w0]     += 2.0f*xc2.x + v0;
      sx2[h*65 + w0 + 1] += 2.0f*xc2.y + v1;
    }
  }
  __syncthreads();
  {
    float wk[9];
    #pragma unroll
    for (int q = 0; q < 9; q++) wk[q] = dww[c*9 + q];
    float dbv = dwb[c];
    int w = tid & 63, st = tid >> 6;
    int h0 = st*16;
    bool wl_ok = (w > 0), wr_ok = (w < 63);
    float r0l, r0c, r0r, r1l, r1c, r1r;
    if (h0 > 0){
      r0l = wl_ok ? sx2[(h0-1)*65 + w-1] : 0.f;
      r0c = sx2[(h0-1)*65 + w];
      r0r = wr_ok ? sx2[(h0-1)*65 + w+1] : 0.f;
    } else { r0l = 0.f; r0c = 0.f; r0r = 0.f; }
    r1l = wl_ok ? sx2[h0*65 + w-1] : 0.f;
    r1c = sx2[h0*65 + w];
    r1r = wr_ok ? sx2[h0*65 + w+1] : 0.f;
    #pragma unroll
    for (int hh2 = 0; hh2 < 16; hh2++){
      int h = h0 + hh2;
      float r2l, r2c, r2r;
      if (h < 63){
        r2l = wl_ok ? sx2[(h+1)*65 + w-1] : 0.f;
        r2c = sx2[(h+1)*65 + w];
        r2r = wr_ok ? sx2[(h+1)*65 + w+1] : 0.f;
      } else { r2l = 0.f; r2c = 0.f; r2r = 0.f; }
      float acc = dbv + r0l*wk[0] + r0c*wk[1] + r0r*wk[2]
                      + r1l*wk[3] + r1c*wk[4] + r1r*wk[5]
                      + r2l*wk[6] + r2c*wk[7] + r2r*wk[8];
      scratch[h*65 + w] = acc / (1.f + __expf(-acc));
      r0l = r1l; r0c = r1c; r0r = r1r;
      r1l = r2l; r1c = r2c; r1r = r2r;
    }
  }
  __syncthreads();
  float* abp = ab + (size_t)plane*4096;
  float* aTp = aT + (size_t)plane*4096;
  for (int p = tid; p < 4096; p += 256){
    abp[p] = scratch[(p >> 6)*65 + (p & 63)];
    aTp[p] = scratch[(p & 63)*65 + (p >> 6)];
  }
}

// ------------------------------------------------ K10: x_proj; wave-split GEMM
__global__ __launch_bounds__(256) void k_xproj(const float* __restrict__ ab,
    const float* __restrict__ aT, const float* __restrict__ xpw,
    float* __restrict__ Bsb, float* __restrict__ Csb, float* __restrict__ dlsb,
    float* __restrict__ xsb){
  int bid = blockIdx.x;
  int s = bid & 63; int k = (bid >> 6) & 3; int b = bid >> 8;
  int tid = threadIdx.x;
  __shared__ float als[96][65];
  __shared__ float dls[6][64];
  int l0 = s << 6;
  const float* src = (k & 1) ? aT : ab;
  bool rev = (k >= 2);
  int i = tid & 63, wg = tid >> 6;
  const float* wr[10];
  #pragma unroll
  for (int r = 0; r < 10; r++){
    int cp = wg + 4*r; if (cp > 37) cp = 37;
    int off = __builtin_amdgcn_readfirstlane((k*38 + cp)*192);
    wr[r] = xpw + off;
  }
  float acc[10];
  #pragma unroll
  for (int r = 0; r < 10; r++) acc[r] = 0.f;
  size_t xbase = ((size_t)(b*4 + k)*4096 + l0)*192;
  #pragma unroll
  for (int half = 0; half < 2; half++){
    int d0 = half*96;
    for (int idx = tid; idx < 1536; idx += 256){
      int d = idx >> 4, i4 = idx & 15;
      const float* rowp = src + ((size_t)b*192 + d0 + d)*4096;
      if (!rev){
        float4 v = *(const float4*)&rowp[l0 + 4*i4];
        als[d][4*i4+0] = v.x; als[d][4*i4+1] = v.y;
        als[d][4*i4+2] = v.z; als[d][4*i4+3] = v.w;
      } else {
        float4 v = *(const float4*)&rowp[4092 - l0 - 4*i4];
        als[d][4*i4+0] = v.w; als[d][4*i4+1] = v.z;
        als[d][4*i4+2] = v.y; als[d][4*i4+3] = v.x;
      }
    }
    __syncthreads();
    for (int d = 0; d < 96; d++){
      float v = als[d][i];
      #pragma unroll
      for (int r = 0; r < 10; r++) acc[r] += v*wr[r][d0 + d];
    }
    for (int idx = tid; idx < 1536; idx += 256){
      int ii = idx / 24, cc = (idx - (idx/24)*24)*4;
      float4 v;
      v.x = als[cc+0][ii]; v.y = als[cc+1][ii];
      v.z = als[cc+2][ii]; v.w = als[cc+3][ii];
      *(float4*)&xsb[xbase + (size_t)ii*192 + d0 + cc] = v;
    }
    __syncthreads();
  }
  #pragma unroll
  for (int r = 0; r < 10; r++){
    int cp = wg + 4*r;
    if (cp > 37) continue;
    if (cp < 6) dls[cp][i] = acc[r];
    else if (cp < 22) Bsb[((size_t)(b*4 + k)*16 + (cp - 6 ))*4096 + l0 + i] = acc[r];
    else              Csb[((size_t)(b*4 + k)*16 + (cp - 22))*4096 + l0 + i] = acc[r];
  }
  __syncthreads();
  size_t dbase = (size_t)((b*4 + k)*64 + s)*384;
  for (int j = tid; j < 384; j += 256){
    int ii = j/6, r = j - ii*6;
    dlsb[dbase + j] = dls[r][ii];
  }
}

// ------------------------------------------------ K11: scan phase A (fast-exp, cheap softplus)
__global__ __launch_bounds__(192) void k_scanA(const float* __restrict__ xsb,
    const float* __restrict__ dlsb, const float* __restrict__ Bsb,
    const float* __restrict__ dtw, const float* __restrict__ dtb,
    const float* __restrict__ alog, float* __restrict__ Pb, float* __restrict__ Qb){
  int bid = blockIdx.x; int s = bid & 63; int k = (bid >> 6) & 3; int b = bid >> 8;
  int c = threadIdx.x; int bk = b*4 + k;
  __shared__ float sdl[384];
  __shared__ float sB[16][64];
  size_t dbase = (size_t)(bk*64 + s)*384;
  for (int j = c; j < 384; j += 192) sdl[j] = dlsb[dbase + j];
  for (int j = c; j < 1024; j += 192){ int n = j >> 6, i = j & 63;
    sB[n][i] = Bsb[((size_t)bk*16 + n)*4096 + (s << 6) + i]; }
  __syncthreads();
  float A[16], P[16], Q[16];
  const float* arow = alog + ((size_t)k*192 + c)*16;
  bool fast = true;
  #pragma unroll
  for (int n = 0; n < 16; n++){
    A[n] = -__expf(arow[n]); P[n] = 1.f; Q[n] = 0.f;
    if (fabsf(A[n] + (float)(n+1)) > 1e-3f) fast = false;
  }
  float dw[6];
  #pragma unroll
  for (int r = 0; r < 6; r++) dw[r] = dtw[((size_t)k*192 + c)*6 + r];
  float db = dtb[k*192 + c];
  const float* xrow = xsb + ((size_t)bk*4096 + (s << 6))*192 + c;
  if (fast){
    for (int i = 0; i < 64; i++){
      float u = xrow[(size_t)i*192];
      float acc = db;
      #pragma unroll
      for (int r = 0; r < 6; r++) acc += sdl[i*6 + r]*dw[r];
      float ec = __expf(fminf(acc, 80.f));
      float dl = __logf(1.f + ec);
      float e1 = __builtin_amdgcn_rcpf(1.f + ec);
      float du = dl*u;
      float e = 1.f;
      #pragma unroll
      for (int n = 0; n < 16; n++){
        e *= e1;
        P[n] *= e;
        Q[n] = Q[n]*e + du*sB[n][i];
      }
    }
  } else {
    for (int i = 0; i < 64; i++){
      float u = xrow[(size_t)i*192];
      float acc = db;
      #pragma unroll
      for (int r = 0; r < 6; r++) acc += sdl[i*6 + r]*dw[r];
      float ec = __expf(fminf(acc, 80.f));
      float dl = __logf(1.f + ec);
      float du = dl*u;
      #pragma unroll
      for (int n = 0; n < 16; n++){
        float e = __expf(dl*A[n]);
        P[n] *= e;
        Q[n] = Q[n]*e + du*sB[n][i];
      }
    }
  }
  size_t pbase = ((size_t)(bk*64 + s)*16)*192 + c;
  #pragma unroll
  for (int n = 0; n < 16; n++){ Pb[pbase + (size_t)n*192] = P[n]; Qb[pbase + (size_t)n*192] = Q[n]; }
}

// ------------------------------------------------ K12: scan phase B (hin in-place over Pb)
__global__ __launch_bounds__(256) void k_scanB(float* __restrict__ Pb,
    const float* __restrict__ Qb){
  int id = blockIdx.x*256 + threadIdx.x;
  int c = id % 192; int rest = id / 192; int n = rest % 16; int bk = rest / 16;
  float h = 0.f;
  for (int s = 0; s < 64; s++){
    size_t o = (((size_t)bk*64 + s)*16 + n)*192 + c;
    float P = Pb[o], Q = Qb[o];
    Pb[o] = h;
    h = P*h + Q;
  }
}

// ------------------------------------------------ K13a: scan phase C — non-atomic, scan-order Y writes
__global__ __launch_bounds__(192) void k_scanC_buf(const float* __restrict__ xsb,
    const float* __restrict__ dlsb, const float* __restrict__ Bsb, const float* __restrict__ Csb,
    const float* __restrict__ hinb, const float* __restrict__ dtw, const float* __restrict__ dtb,
    const float* __restrict__ alog, const float* __restrict__ Dsp, float* __restrict__ Y){
  int bid = blockIdx.x; int s = bid & 63; int k = (bid >> 6) & 3; int b = bid >> 8;
  int c = threadIdx.x; int bk = b*4 + k;
  __shared__ float sdl[384];
  __shared__ float sB[16][64];
  __shared__ float sC[16][64];
  size_t dbase = (size_t)(bk*64 + s)*384;
  for (int j = c; j < 384; j += 192) sdl[j] = dlsb[dbase + j];
  for (int j = c; j < 1024; j += 192){ int n = j >> 6, i = j & 63;
    size_t o = ((size_t)bk*16 + n)*4096 + (s << 6) + i;
    sB[n][i] = Bsb[o]; sC[n][i] = Csb[o]; }
  __syncthreads();
  float A[16], h[16];
  const float* arow = alog + ((size_t)k*192 + c)*16;
  bool fast = true;
  #pragma unroll
  for (int n = 0; n < 16; n++){
    A[n] = -__expf(arow[n]);
    if (fabsf(A[n] + (float)(n+1)) > 1e-3f) fast = false;
  }
  size_t hbase = ((size_t)(bk*64 + s)*16)*192 + c;
  #pragma unroll
  for (int n = 0; n < 16; n++) h[n] = hinb[hbase + (size_t)n*192];
  float dw[6];
  #pragma unroll
  for (int r = 0; r < 6; r++) dw[r] = dtw[((size_t)k*192 + c)*6 + r];
  float db = dtb[k*192 + c];
  float Dc = Dsp[k*192 + c];
  const float* xrow = xsb + ((size_t)bk*4096 + (s << 6))*192 + c;
  float* Yk = Y + (((size_t)bk*4096 + (s << 6))*192) + c;
  if (fast){
    for (int i = 0; i < 64; i++){
      float u = xrow[(size_t)i*192];
      float acc = db;
      #pragma unroll
      for (int r = 0; r < 6; r++) acc += sdl[i*6 + r]*dw[r];
      float ec = __expf(fminf(acc, 80.f));
      float dl = __logf(1.f + ec);
      float e1 = __builtin_amdgcn_rcpf(1.f + ec);
      float du = dl*u;
      float e = 1.f;
      float y = 0.f;
      #pragma unroll
      for (int n = 0; n < 16; n++){
        e *= e1;
        h[n] = h[n]*e + du*sB[n][i];
        y += h[n]*sC[n][i];
      }
      Yk[(size_t)i*192] = y + u*Dc;
    }
  } else {
    for (int i = 0; i < 64; i++){
      float u = xrow[(size_t)i*192];
      float acc = db;
      #pragma unroll
      for (int r = 0; r < 6; r++) acc += sdl[i*6 + r]*dw[r];
      float ec = __expf(fminf(acc, 80.f));
      float dl = __logf(1.f + ec);
      float du = dl*u;
      float y = 0.f;
      #pragma unroll
      for (int n = 0; n < 16; n++){
        float e = __expf(dl*A[n]);
        h[n] = h[n]*e + du*sB[n][i];
        y += h[n]*sC[n][i];
      }
      Yk[(size_t)i*192] = y + u*Dc;
    }
  }
}

// ------------------------------------------------ K13b: scan phase C — atomic fallback
__global__ __launch_bounds__(192) void k_scanC_atom(const float* __restrict__ xsb,
    const float* __restrict__ dlsb, const float* __restrict__ Bsb, const float* __restrict__ Csb,
    const float* __restrict__ hinb, const float* __restrict__ dtw, const float* __restrict__ dtb,
    const float* __restrict__ alog, const float* __restrict__ Dsp, float* __restrict__ yb){
  int bid = blockIdx.x; int s = bid & 63; int k = (bid >> 6) & 3; int b = bid >> 8;
  int c = threadIdx.x; int bk = b*4 + k;
  __shared__ float sdl[384];
  __shared__ float sB[16][64];
  __shared__ float sC[16][64];
  size_t dbase = (size_t)(bk*64 + s)*384;
  for (int j = c; j < 384; j += 192) sdl[j] = dlsb[dbase + j];
  for (int j = c; j < 1024; j += 192){ int n = j >> 6, i = j & 63;
    size_t o = ((size_t)bk*16 + n)*4096 + (s << 6) + i;
    sB[n][i] = Bsb[o]; sC[n][i] = Csb[o]; }
  __syncthreads();
  float A[16], h[16];
  const float* arow = alog + ((size_t)k*192 + c)*16;
  bool fast = true;
  #pragma unroll
  for (int n = 0; n < 16; n++){
    A[n] = -__expf(arow[n]);
    if (fabsf(A[n] + (float)(n+1)) > 1e-3f) fast = false;
  }
  size_t hbase = ((size_t)(bk*64 + s)*16)*192 + c;
  #pragma unroll
  for (int n = 0; n < 16; n++) h[n] = hinb[hbase + (size_t)n*192];
  float dw[6];
  #pragma unroll
  for (int r = 0; r < 6; r++) dw[r] = dtw[((size_t)k*192 + c)*6 + r];
  float db = dtb[k*192 + c];
  float Dc = Dsp[k*192 + c];
  const float* xrow = xsb + ((size_t)bk*4096 + (s << 6))*192 + c;
  int p0, pst;
  if (k == 0){ p0 = s << 6;        pst = 1;  }
  else if (k == 1){ p0 = s;        pst = 64; }
  else if (k == 2){ p0 = 4095 - (s << 6); pst = -1; }
  else { p0 = 4095 - s;            pst = -64; }
  for (int i = 0; i < 64; i++){
    float u = xrow[(size_t)i*192];
    float acc = db;
    #pragma unroll
    for (int r = 0; r < 6; r++) acc += sdl[i*6 + r]*dw[r];
    float ec = __expf(fminf(acc, 80.f));
    float dl = __logf(1.f + ec);
    float du = dl*u;
    float y = 0.f;
    if (fast){
      float e1 = __builtin_amdgcn_rcpf(1.f + ec);
      float e = 1.f;
      #pragma unroll
      for (int n = 0; n < 16; n++){
        e *= e1;
        h[n] = h[n]*e + du*sB[n][i];
        y += h[n]*sC[n][i];
      }
    } else {
      #pragma unroll
      for (int n = 0; n < 16; n++){
        float e = __expf(dl*A[n]);
        h[n] = h[n]*e + du*sB[n][i];
        y += h[n]*sC[n][i];
      }
    }
    y += u*Dc;
    atomicAdd(&yb[((size_t)b*4096 + p0 + pst*i)*192 + c], y);
  }
}

// ------------------------------------------------ K14b: symmetry enhance (atomic path)
__global__ __launch_bounds__(256) void k_enh(const float* __restrict__ yb,
    const float* __restrict__ symw, float* __restrict__ yfb){
  int id = blockIdx.x*256 + threadIdx.x;
  int c = id % 192; int rest = id / 192; int l = rest & 4095; int b = rest >> 12;
  int w = l & 63; int lr = (l | 63) - w;
  float v  = yb[id];
  float vr = yb[(((size_t)b << 12) + lr)*192 + c];
  float wg = 1.f/(1.f + __expf(-symw[0]));
  float enh = v*(1.f - wg) + 0.5f*(v + vr)*wg;
  yfb[id] = v + 0.2f*enh;
}

// ------------------------------------------------ K15a (fused, bigws): gather scan-order Y + enh + LN + out_proj
// v4: 32 mirror-pair rows, wt staged in TWO 96-c halves (LDS ~45 KB => 3 blocks/CU).
__global__ __launch_bounds__(256) void k_final_comb(const float* __restrict__ Y,
    const float* __restrict__ symw, const float* __restrict__ zT,
    const float* __restrict__ g, const float* __restrict__ bta,
    const float* __restrict__ opw, const float* __restrict__ x, float* __restrict__ out){
  int og = blockIdx.x & 1; int lt = (blockIdx.x >> 1) & 127; int b = blockIdx.x >> 8;
  int h = lt >> 1, wsel = lt & 1;
  __shared__ float sv[32][193];
  __shared__ float wtb[96*48];
  __shared__ float sg[192], sb2[192];
  __shared__ float smu[32], srs[32];
  __shared__ int lmap[32];
  int tid = threadIdx.x;
  const size_t S = (size_t)4096*192;
  float wg = 1.f/(1.f + __expf(-symw[0]));
  if (tid < 32){
    int r = tid;
    int w = (r < 16) ? (wsel*16 + r) : (63 - wsel*16 - (r - 16));
    lmap[r] = h*64 + w;
  }
  for (int idx = tid; idx < 1536; idx += 256){
    int r = idx / 48, c4 = (idx - (idx/48)*48)*4;
    int w = (r < 16) ? (wsel*16 + r) : (63 - wsel*16 - (r - 16));
    int l = h*64 + w;
    int p1 = (w << 6) | h;
    size_t base = (size_t)(b*4)*S + c4;
    float4 v0 = *(const float4*)&Y[base + (size_t)l*192];
    float4 v1 = *(const float4*)&Y[base + S + (size_t)p1*192];
    float4 v2 = *(const float4*)&Y[base + 2*S + (size_t)(4095 - l)*192];
    float4 v3 = *(const float4*)&Y[base + 3*S + (size_t)(4095 - p1)*192];
    sv[r][c4+0] = v0.x + v1.x + v2.x + v3.x;
    sv[r][c4+1] = v0.y + v1.y + v2.y + v3.y;
    sv[r][c4+2] = v0.z + v1.z + v2.z + v3.z;
    sv[r][c4+3] = v0.w + v1.w + v2.w + v3.w;
  }
  if (tid < 192){ sg[tid] = g[tid]; sb2[tid] = bta[tid]; }
  int o0 = og*48;
  // stage wt half-1: c in [0,96)
  for (int idx = tid; idx < 4608; idx += 256){ int o = idx % 48, c = idx/48;
    wtb[c*48 + o] = opw[(size_t)(o0 + o)*192 + c]; }
  __syncthreads();
  float yreg[24];
  #pragma unroll
  for (int t = 0; t < 24; t++){
    int idx = tid + t*256;
    int r = idx / 192, cc = idx - r*192;
    int rp = (r < 16) ? r + 16 : r - 16;
    float v = sv[r][cc], vp = sv[rp][cc];
    float enh = v*(1.f - wg) + 0.5f*(v + vp)*wg;
    yreg[t] = v + 0.2f*enh;
  }
  __syncthreads();
  #pragma unroll
  for (int t = 0; t < 24; t++){
    int idx = tid + t*256;
    int r = idx / 192, cc = idx - r*192;
    sv[r][cc] = yreg[t];
  }
  __syncthreads();
  if (tid < 32){
    float s1 = 0.f, s2 = 0.f;
    for (int c = 0; c < 192; c++){ float v = sv[tid][c]; s1 += v; s2 += v*v; }
    float mu = s1*(1.0f/192.0f);
    smu[tid] = mu; srs[tid] = rsqrtf(s2*(1.0f/192.0f) - mu*mu + 1e-5f);
  }
  __syncthreads();
  for (int idx = tid; idx < 6144; idx += 256){ int l = idx & 31, c = idx >> 5;
    float zv = zT[((size_t)b*192 + c)*4096 + lmap[l]];
    float v = sv[l][c];
    float yn = (v - smu[l])*srs[l]*sg[c] + sb2[c];
    sv[l][c] = yn * (zv/(1.f + __expf(-zv)));
  }
  __syncthreads();
  int l = tid & 31, grp = tid >> 5;
  float acc[6];
  #pragma unroll
  for (int j = 0; j < 6; j++) acc[j] = 0.f;
  // GEMM part 1: c in [0,96)
  for (int c = 0; c < 96; c++){
    float svv = sv[l][c];
    const float* wr = &wtb[c*48 + grp*6];
    #pragma unroll
    for (int j = 0; j < 6; j += 2){
      float2 w2 = *(const float2*)&wr[j];
      acc[j]   += svv*w2.x; acc[j+1] += svv*w2.y;
    }
  }
  __syncthreads();
  // stage wt half-2: c in [96,192)
  for (int idx = tid; idx < 4608; idx += 256){ int o = idx % 48, c = idx/48;
    wtb[c*48 + o] = opw[(size_t)(o0 + o)*192 + 96 + c]; }
  __syncthreads();
  for (int c = 0; c < 96; c++){
    float svv = sv[l][96 + c];
    const float* wr = &wtb[c*48 + grp*6];
    #pragma unroll
    for (int j = 0; j < 6; j += 2){
      float2 w2 = *(const float2*)&wr[j];
      acc[j]   += svv*w2.x; acc[j+1] += svv*w2.y;
    }
  }
  size_t ob = ((size_t)b*4096 + lmap[l])*96 + o0 + grp*6;
  #pragma unroll
  for (int j = 0; j < 6; j++) acc[j] += x[ob + j];
  #pragma unroll
  for (int j = 0; j < 6; j += 2){
    float2 v2; v2.x = acc[j]; v2.y = acc[j+1];
    *(float2*)&out[ob + j] = v2;
  }
}

// ------------------------------------------------ K15b: fallback
__global__ __launch_bounds__(256) void k_final(const float* __restrict__ yf,
    const float* __restrict__ zT, const float* __restrict__ g, const float* __restrict__ bta,
    const float* __restrict__ opw, const float* __restrict__ x, float* __restrict__ out){
  int og = blockIdx.x & 1; int lt = (blockIdx.x >> 1) & 127; int b = blockIdx.x >> 8;
  int l0 = lt << 5;
  __shared__ float sv[32][193];
  __shared__ float wt[192*48];
  __shared__ float sg[192], sb2[192];
  __shared__ float smu[32], srs[32];
  int tid = threadIdx.x;
  for (int idx = tid; idx < 6144; idx += 256){ int r = idx/192, c = idx - r*192;
    sv[r][c] = yf[((size_t)b*4096 + l0 + r)*192 + c]; }
  if (tid < 192){ sg[tid] = g[tid]; sb2[tid] = bta[tid]; }
  int o0 = og*48;
  for (int idx = tid; idx < 9216; idx += 256){ int o = idx % 48, c = idx/48;
    wt[c*48 + o] = opw[(size_t)(o0 + o)*192 + c]; }
  __syncthreads();
  if (tid < 32){
    float s1 = 0.f, s2 = 0.f;
    for (int c = 0; c < 192; c++){ float v = sv[tid][c]; s1 += v; s2 += v*v; }
    float mu = s1*(1.0f/192.0f);
    smu[tid] = mu; srs[tid] = rsqrtf(s2*(1.0f/192.0f) - mu*mu + 1e-5f);
  }
  __syncthreads();
  for (int idx = tid; idx < 6144; idx += 256){ int l = idx & 31, c = idx >> 5;
    float zv = zT[((size_t)b*192 + c)*4096 + l0 + l];
    float v = sv[l][c];
    float yn = (v - smu[l])*srs[l]*sg[c] + sb2[c];
    sv[l][c] = yn * (zv/(1.f + __expf(-zv)));
  }
  __syncthreads();
  int l = tid & 31, grp = tid >> 5;
  float acc[6];
  #pragma unroll
  for (int j = 0; j < 6; j++) acc[j] = 0.f;
  for (int c = 0; c < 192; c++){
    float svv = sv[l][c];
    const float* wr = &wt[c*48 + grp*6];
    #pragma unroll
    for (int j = 0; j < 6; j += 2){
      float2 w2 = *(const float2*)&wr[j];
      acc[j]   += svv*w2.x; acc[j+1] += svv*w2.y;
    }
  }
  size_t ob = ((size_t)b*4096 + l0 + l)*96 + o0 + grp*6;
  #pragma unroll
  for (int j = 0; j < 6; j++) acc[j] += x[ob + j];
  #pragma unroll
  for (int j = 0; j < 6; j += 2){
    float2 v2; v2.x = acc[j]; v2.y = acc[j+1];
    *(float2*)&out[ob + j] = v2;
  }
}

// ================================================================ host
extern "C" void kernel_launch(void* const* d_in, const int* in_sizes, int n_in,
                              void* d_out, int out_size, void* d_ws, size_t ws_size,
                              hipStream_t stream){
  (void)in_sizes; (void)n_in; (void)out_size;
  const float* ix   = (const float*)d_in[0];
  const float* ipw  = (const float*)d_in[1];
  const float* fw1  = (const float*)d_in[2];
  const float* fb1  = (const float*)d_in[3];
  const float* fw2  = (const float*)d_in[4];
  const float* fb2  = (const float*)d_in[5];
  const float* ww   = (const float*)d_in[6];
  const float* wb   = (const float*)d_in[7];
  const float* dww  = (const float*)d_in[8];
  const float* dwb  = (const float*)d_in[9];
  const float* symw = (const float*)d_in[10];
  const float* xpw  = (const float*)d_in[11];
  const float* dtw  = (const float*)d_in[12];
  const float* dtb  = (const float*)d_in[13];
  const float* alog = (const float*)d_in[14];
  const float* Dsp  = (const float*)d_in[15];
  const float* ong  = (const float*)d_in[16];
  const float* onb  = (const float*)d_in[17];
  const float* opw  = (const float*)d_in[18];
  const float* rmsw = (const float*)d_in[19];

  float* W = (float*)d_ws;
  const size_t SZ_BLC = 3145728, SZ_F = 1622016, SZ_H = 786432;
  float* zT  = W;
  float* ab  = zT + SZ_BLC;
  float* R0  = ab + SZ_BLC;
  // phase 1
  float* xc    = R0;
  float* fre   = xc  + SZ_BLC;
  float* fim   = fre + SZ_F;
  float* fab   = fim + SZ_F;
  float* mb    = fab + SZ_F;
  float* llb   = mb  + SZ_F;
  float* lhb   = llb + SZ_H;
  float* wnew  = lhb + 3*SZ_H;
  unsigned short* wqb2 = (unsigned short*)(wnew + 2359296);
  unsigned short* lhT  = wqb2 + 331776;   // 12 img x 1024 pix x 192 ic, bf16 (2.36M shorts)
  // phase 2
  float* Bsb  = R0;
  float* Csb  = Bsb + 1048576;
  float* dlsb = Csb + 1048576;
  float* xsb  = dlsb + 393216;
  float* Pb   = xsb + 12582912;
  float* aT   = Pb;
  float* Qb   = Pb + SZ_BLC;
  float* Yb   = Qb;                  // scan-order Y [bk][iscan][c]
  float* ybA  = Qb + SZ_BLC;
  float* yfb  = xsb;

  const size_t NEED_BIG = (size_t)(6291456 + 30801920) * 4;
  bool bigws = (ws_size >= NEED_BIG);

  hipLaunchKernelGGL(k_rms_inproj, dim3(2048),   dim3(256), 0, stream, ix, rmsw, ipw, xc, zT);
  hipLaunchKernelGGL(k_dft_fwd,    dim3(4*192),  dim3(256), 0, stream, xc, fre, fim, fab,
                     llb, lhb, lhb + SZ_H, lhb + 2*SZ_H);
  hipLaunchKernelGGL(k_cvt_w,      dim3(1296),   dim3(256), 0, stream, ww, wqb2);
  hipLaunchKernelGGL(k_prep_lhT,   dim3(1152),   dim3(256), 0, stream, lhb, lhT);
  hipLaunchKernelGGL(k_cmix1,      dim3(864),    dim3(256), 0, stream, fab, fw1, fb1, mb);
  hipLaunchKernelGGL(k_cmix2,      dim3(864),    dim3(256), 0, stream, mb, fw2, fb2, fre, fim, fab);
  hipLaunchKernelGGL(k_wconv_mfma, dim3(576),    dim3(256), 0, stream, lhT, wqb2, wnew);
  hipLaunchKernelGGL(k_ifwd,       dim3(768),    dim3(256), 0, stream, fre, fim, xc, llb, wnew, wb, dww, dwb, ab, aT);
  hipLaunchKernelGGL(k_xproj,      dim3(1024),   dim3(256), 0, stream, ab, aT, xpw, Bsb, Csb, dlsb, xsb);
  hipLaunchKernelGGL(k_scanA,      dim3(1024),   dim3(192), 0, stream, xsb, dlsb, Bsb, dtw, dtb, alog, Pb, Qb);
  hipLaunchKernelGGL(k_scanB,      dim3(192),    dim3(256), 0, stream, Pb, Qb);
  if (bigws){
    hipLaunchKernelGGL(k_scanC_buf,  dim3(1024), dim3(192), 0, stream, xsb, dlsb, Bsb, Csb, Pb, dtw, dtb, alog, Dsp, Yb);
    hipLaunchKernelGGL(k_final_comb, dim3(1024), dim3(256), 0, stream, Yb, symw, zT, ong, onb, opw, ix, (float*)d_out);
  } else {
    hipLaunchKernelGGL(k_zero,       dim3(12288), dim3(256), 0, stream, ybA, (int)SZ_BLC);
    hipLaunchKernelGGL(k_scanC_atom, dim3(1024),  dim3(192), 0, stream, xsb, dlsb, Bsb, Csb, Pb, dtw, dtb, alog, Dsp, ybA);
    hipLaunchKernelGGL(k_enh,        dim3(12288), dim3(256), 0, stream, ybA, symw, yfb);
    hipLaunchKernelGGL(k_final,      dim3(1024),  dim3(256), 0, stream, yfb, zT, ong, onb, opw, ix, (float*)d_out);
  }
}